// Round 2
// baseline (2749.463 us; speedup 1.0000x reference)
//
#include <hip/hip_runtime.h>
#include <cstdint>
#include <cstddef>

// ---------------- problem constants ----------------
#define N_NODES 20000
#define N_EDGES 160000
#define HIDDEN  512
#define NHEAD   8
#define HDK     64
#define NLAYER  4
#define FFDIM   2048
#define ATT_SCALE 0.125f   // 1/sqrt(64)

// ---------------- MFMA types ----------------
typedef float  f4  __attribute__((ext_vector_type(4)));
typedef short  s8v __attribute__((ext_vector_type(8)));
typedef __bf16 b8v __attribute__((ext_vector_type(8)));

// Hedge: accept either builtin signature (short8 or bf16x8).
template <typename V>
__device__ inline auto mfma_try(V a, V b, f4 c, int)
    -> decltype(__builtin_amdgcn_mfma_f32_16x16x32_bf16(a, b, c, 0, 0, 0)) {
  return __builtin_amdgcn_mfma_f32_16x16x32_bf16(a, b, c, 0, 0, 0);
}
template <typename V>
__device__ inline f4 mfma_try(V a, V b, f4 c, long) {
  return __builtin_amdgcn_mfma_f32_16x16x32_bf16(
      __builtin_bit_cast(b8v, a), __builtin_bit_cast(b8v, b), c, 0, 0, 0);
}
__device__ inline f4 mfma_bf16(s8v a, s8v b, f4 c) { return mfma_try(a, b, c, 0); }

__device__ __forceinline__ unsigned short f2bf(float f) {
  unsigned u = __builtin_bit_cast(unsigned, f);
  u += 0x7FFFu + ((u >> 16) & 1u);   // RNE
  return (unsigned short)(u >> 16);
}
__device__ __forceinline__ float bf2f(unsigned short u) {
  return __builtin_bit_cast(float, (unsigned)u << 16);
}

// ---------------- weight transpose + bf16 cast: in (K x N) fp32 -> out (N x K) bf16 ----------------
__global__ void transpose_cast_kernel(const float* __restrict__ in,
                                      unsigned short* __restrict__ out,
                                      int K, int N) {
  __shared__ float t[32][33];
  int tx = threadIdx.x, ty = threadIdx.y;
  int n0 = blockIdx.x * 32, k0 = blockIdx.y * 32;
#pragma unroll
  for (int i = 0; i < 32; i += 8)
    t[ty + i][tx] = in[(size_t)(k0 + ty + i) * N + n0 + tx];
  __syncthreads();
#pragma unroll
  for (int i = 0; i < 32; i += 8)
    out[(size_t)(n0 + ty + i) * K + k0 + tx] = f2bf(t[tx][ty + i]);
}

// ---------------- GEMM: C[M,N] = A[M,K] @ Bt[N,K]^T + bias, optional relu ----------------
// A row-major (fp32 or bf16 per ABF16), Bt bf16 pre-transposed weight.
// Output fp32 or bf16 per OBF16.
#define BM 128
#define BN 128
#define BK 32
#define LDT 40   // padded LDS stride (bf16 elems): 80B stride, 16B-aligned vectors, <=2-way bank alias

template <bool ABF16, bool OBF16>
__global__ __launch_bounds__(256) void gemm_kernel(
    const void* __restrict__ Ap, const unsigned short* __restrict__ Bt,
    const float* __restrict__ bias, void* __restrict__ Cp,
    int M, int K, int N, int relu) {
  __shared__ __align__(16) unsigned short As[BM * LDT];
  __shared__ __align__(16) unsigned short Bs[BN * LDT];
  int tid = threadIdx.x;
  int wave = tid >> 6, lane = tid & 63;
  int quad = lane >> 4, l16 = lane & 15;
  int wm = (wave >> 1) * 64, wn = (wave & 1) * 64;
  int m0 = blockIdx.x * BM, n0 = blockIdx.y * BN;

  f4 acc[4][4];
#pragma unroll
  for (int i = 0; i < 4; ++i)
#pragma unroll
    for (int j = 0; j < 4; ++j) acc[i][j] = (f4){0.f, 0.f, 0.f, 0.f};

  int nsteps = K / BK;
  for (int ks = 0; ks < nsteps; ++ks) {
    // ---- stage A tile (128 x 32) ----
    if constexpr (ABF16) {
      const unsigned short* A = (const unsigned short*)Ap;
#pragma unroll
      for (int r = 0; r < 2; ++r) {
        int idx = tid + r * 256;        // 0..511
        int row = idx >> 2;
        int col = (idx & 3) * 8;
        int gm = m0 + row;
        s8v va = {};
        if (gm < M) va = *(const s8v*)(A + (size_t)gm * K + ks * BK + col);
        *(s8v*)(&As[row * LDT + col]) = va;
      }
    } else {
      const float* A = (const float*)Ap;
#pragma unroll
      for (int r = 0; r < 4; ++r) {
        int idx = tid + r * 256;        // 0..1023
        int row = idx >> 3;
        int col = (idx & 7) * 4;
        int gm = m0 + row;
        float4 val = make_float4(0.f, 0.f, 0.f, 0.f);
        if (gm < M) val = *(const float4*)(A + (size_t)gm * K + ks * BK + col);
        ushort4 h;
        h.x = f2bf(val.x); h.y = f2bf(val.y); h.z = f2bf(val.z); h.w = f2bf(val.w);
        *(ushort4*)(&As[row * LDT + col]) = h;
      }
    }
    // ---- stage B tile (128 x 32, already bf16) ----
#pragma unroll
    for (int r = 0; r < 2; ++r) {
      int idx = tid + r * 256;          // 0..511
      int row = idx >> 2;
      int col = (idx & 3) * 8;
      s8v vb = *(const s8v*)(Bt + (size_t)(n0 + row) * K + ks * BK + col);
      *(s8v*)(&Bs[row * LDT + col]) = vb;
    }
    __syncthreads();
    s8v af[4], bfr[4];
#pragma unroll
    for (int i = 0; i < 4; ++i) {
      af[i]  = *(const s8v*)(&As[(wm + i * 16 + l16) * LDT + quad * 8]);
      bfr[i] = *(const s8v*)(&Bs[(wn + i * 16 + l16) * LDT + quad * 8]);
    }
#pragma unroll
    for (int mi = 0; mi < 4; ++mi)
#pragma unroll
      for (int ni = 0; ni < 4; ++ni)
        acc[mi][ni] = mfma_bf16(af[mi], bfr[ni], acc[mi][ni]);
    __syncthreads();
  }
  // epilogue: D[row=(lane>>4)*4+r][col=lane&15]
#pragma unroll
  for (int ni = 0; ni < 4; ++ni) {
    int col = n0 + wn + ni * 16 + l16;
    float bv = bias[col];
#pragma unroll
    for (int mi = 0; mi < 4; ++mi) {
#pragma unroll
      for (int r = 0; r < 4; ++r) {
        int row = m0 + wm + mi * 16 + quad * 4 + r;
        if (row < M) {
          float val = acc[mi][ni][r] + bv;
          if (relu) val = fmaxf(val, 0.f);
          if constexpr (OBF16)
            ((unsigned short*)Cp)[(size_t)row * N + col] = f2bf(val);
          else
            ((float*)Cp)[(size_t)row * N + col] = val;
        }
      }
    }
  }
}

// ---------------- CSR build ----------------
__global__ void hist_kernel(const int* __restrict__ dst, int* __restrict__ cnt, int E) {
  int e = blockIdx.x * blockDim.x + threadIdx.x;
  if (e < E) atomicAdd(&cnt[dst[e]], 1);
}

__global__ void scan_kernel(const int* __restrict__ cnt, int* __restrict__ offs, int n) {
  __shared__ int sh[1024];
  __shared__ int carry_sh;
  int tid = threadIdx.x;
  if (tid == 0) carry_sh = 0;
  __syncthreads();
  for (int base = 0; base < n; base += 1024) {
    int v = (base + tid < n) ? cnt[base + tid] : 0;
    sh[tid] = v;
    __syncthreads();
    for (int s = 1; s < 1024; s <<= 1) {
      int t = (tid >= s) ? sh[tid - s] : 0;
      __syncthreads();
      sh[tid] += t;
      __syncthreads();
    }
    int carry = carry_sh;
    if (base + tid < n) offs[base + tid] = carry + sh[tid] - v;
    __syncthreads();
    if (tid == 1023) carry_sh = carry + sh[1023];
    __syncthreads();
  }
  if (tid == 0) offs[n] = carry_sh;
}

__global__ void scatter_kernel(const int* __restrict__ dst, const int* __restrict__ offs,
                               int* __restrict__ cursor, int* __restrict__ elist, int E) {
  int e = blockIdx.x * blockDim.x + threadIdx.x;
  if (e < E) {
    int d = dst[e];
    int pos = offs[d] + atomicAdd(&cursor[d], 1);
    elist[pos] = e;
  }
}

// ---------------- edge scores: score[e][h] = SCALE * dot(k[src]+rh, q[dst]) ----------------
__global__ void score_kernel(const unsigned short* __restrict__ q,
                             const unsigned short* __restrict__ k,
                             const float* __restrict__ rel, const int* __restrict__ relations,
                             const int* __restrict__ src, const int* __restrict__ dst,
                             float* __restrict__ score, int E) {
  int wid = (blockIdx.x * blockDim.x + threadIdx.x) >> 6;
  int lane = threadIdx.x & 63;
  if (wid >= E) return;
  int s = src[wid], d = dst[wid], r = relations[wid];
  const unsigned short* kr = k + (size_t)s * HIDDEN;
  const unsigned short* qr = q + (size_t)d * HIDDEN;
  const float* rr = rel + (size_t)r * HIDDEN;
#pragma unroll
  for (int h = 0; h < NHEAD; ++h) {
    int idx = h * HDK + lane;
    float p = (bf2f(kr[idx]) + rr[idx]) * bf2f(qr[idx]);
#pragma unroll
    for (int off = 32; off; off >>= 1) p += __shfl_xor(p, off, 64);
    if (lane == 0) score[(size_t)wid * NHEAD + h] = p * ATT_SCALE;
  }
}

// ---------------- per-dst softmax + weighted V aggregation (one wave per node) ----------------
__global__ void aggregate_kernel(const float* __restrict__ score,
                                 const unsigned short* __restrict__ v,
                                 const float* __restrict__ rel, const int* __restrict__ relations,
                                 const int* __restrict__ src, const int* __restrict__ offs,
                                 const int* __restrict__ elist,
                                 unsigned short* __restrict__ o, int Nn) {
  int wid = (blockIdx.x * blockDim.x + threadIdx.x) >> 6;
  int lane = threadIdx.x & 63;
  if (wid >= Nn) return;
  int beg = offs[wid], end = offs[wid + 1];
  float m[NHEAD], z[NHEAD], acc[NHEAD];
#pragma unroll
  for (int h = 0; h < NHEAD; ++h) { m[h] = -1e30f; z[h] = 0.f; acc[h] = 0.f; }
  for (int i = beg + lane; i < end; i += 64) {
    int e = elist[i];
#pragma unroll
    for (int h = 0; h < NHEAD; ++h) m[h] = fmaxf(m[h], score[(size_t)e * NHEAD + h]);
  }
#pragma unroll
  for (int h = 0; h < NHEAD; ++h)
#pragma unroll
    for (int off = 32; off; off >>= 1) m[h] = fmaxf(m[h], __shfl_xor(m[h], off, 64));
  for (int i = beg + lane; i < end; i += 64) {
    int e = elist[i];
#pragma unroll
    for (int h = 0; h < NHEAD; ++h) z[h] += __expf(score[(size_t)e * NHEAD + h] - m[h]);
  }
#pragma unroll
  for (int h = 0; h < NHEAD; ++h)
#pragma unroll
    for (int off = 32; off; off >>= 1) z[h] += __shfl_xor(z[h], off, 64);
  // pass 2: whole wave per edge, lane = d within head
  for (int i = beg; i < end; ++i) {
    int e = elist[i];
    int s = src[e], r = relations[e];
    const unsigned short* vr = v + (size_t)s * HIDDEN;
    const float* rr = rel + (size_t)r * HIDDEN;
#pragma unroll
    for (int h = 0; h < NHEAD; ++h) {
      float w = __expf(score[(size_t)e * NHEAD + h] - m[h]);
      acc[h] += w * (bf2f(vr[h * HDK + lane]) + rr[h * HDK + lane]);
    }
  }
#pragma unroll
  for (int h = 0; h < NHEAD; ++h)
    o[(size_t)wid * HIDDEN + h * HDK + lane] = f2bf(acc[h] / (z[h] + 1e-9f));
}

// ---------------- fused residual add + LayerNorm (one wave per row) ----------------
__global__ void ln_kernel(const float* __restrict__ x, const float* __restrict__ y,
                          const float* __restrict__ g, const float* __restrict__ b,
                          float* __restrict__ out, int Nn) {
  int wid = (blockIdx.x * blockDim.x + threadIdx.x) >> 6;
  int lane = threadIdx.x & 63;
  if (wid >= Nn) return;
  const float* xr = x + (size_t)wid * HIDDEN;
  const float* yr = y + (size_t)wid * HIDDEN;
  float vals[8];
  float sum = 0.f;
#pragma unroll
  for (int j = 0; j < 8; ++j) {
    vals[j] = xr[j * 64 + lane] + yr[j * 64 + lane];
    sum += vals[j];
  }
#pragma unroll
  for (int off = 32; off; off >>= 1) sum += __shfl_xor(sum, off, 64);
  float mean = sum * (1.f / 512.f);
  float sq = 0.f;
#pragma unroll
  for (int j = 0; j < 8; ++j) { float d = vals[j] - mean; sq += d * d; }
#pragma unroll
  for (int off = 32; off; off >>= 1) sq += __shfl_xor(sq, off, 64);
  float rstd = rsqrtf(sq * (1.f / 512.f) + 1e-5f);
#pragma unroll
  for (int j = 0; j < 8; ++j) {
    int idx = j * 64 + lane;
    out[(size_t)wid * HIDDEN + idx] = (vals[j] - mean) * rstd * g[idx] + b[idx];
  }
}

// ---------------- host orchestration ----------------
extern "C" void kernel_launch(void* const* d_in, const int* in_sizes, int n_in,
                              void* d_out, int out_size, void* d_ws, size_t ws_size,
                              hipStream_t stream) {
  const float* x0        = (const float*)d_in[0];
  const int*   relations = (const int*)d_in[1];
  const int*   src       = (const int*)d_in[2];
  const int*   dst       = (const int*)d_in[3];
  const float* rel_embed = (const float*)d_in[4];
  const float* Wq = (const float*)d_in[5];  const float* bq = (const float*)d_in[6];
  const float* Wk = (const float*)d_in[7];  const float* bk = (const float*)d_in[8];
  const float* Wv = (const float*)d_in[9];  const float* bv = (const float*)d_in[10];
  const float* Wo = (const float*)d_in[11]; const float* bo = (const float*)d_in[12];
  const float* W1 = (const float*)d_in[13]; const float* b1 = (const float*)d_in[14];
  const float* W2 = (const float*)d_in[15]; const float* b2 = (const float*)d_in[16];
  const float* g1  = (const float*)d_in[17]; const float* bb1 = (const float*)d_in[18];
  const float* g2  = (const float*)d_in[19]; const float* bb2 = (const float*)d_in[20];
  float* xout = (float*)d_out;

  const size_t S1 = 512 * 512;       // 262144
  const size_t S2 = 512 * 2048;      // 1048576
  const size_t NH = (size_t)N_NODES * HIDDEN;   // 10,240,000

  // ---- lean workspace layout (~168 MiB total) ----
  unsigned short* wq = (unsigned short*)d_ws;   // per-layer reused weight buffers (bf16)
  unsigned short* wk = wq + S1;
  unsigned short* wv = wk + S1;
  unsigned short* wo = wv + S1;
  unsigned short* w1 = wo + S1;                 // S2
  unsigned short* w2 = w1 + S2;                 // S2
  unsigned short* arena = w2 + S2;              // 4*NH bf16: qb|kb|vb|ob, aliased by ff1
  unsigned short* qb = arena;
  unsigned short* kb = arena + NH;
  unsigned short* vb = arena + 2 * NH;
  unsigned short* ob = arena + 3 * NH;
  unsigned short* ff1 = arena;                  // 4*NH bf16 (qkv+ob dead by FF time)
  float* proj  = (float*)(arena + 4 * NH);      // NH fp32
  float* hb    = proj + NH;                     // NH fp32
  float* score = hb + NH;                       // E*8 fp32
  int* cnt    = (int*)(score + (size_t)N_EDGES * NHEAD);
  int* offs   = cnt + N_NODES;
  int* cursor = offs + N_NODES + 1;
  int* elist  = cursor + N_NODES;

  // ---- CSR build (once per call; shared across layers) ----
  hipMemsetAsync(cnt, 0, N_NODES * sizeof(int), stream);
  hipMemsetAsync(cursor, 0, N_NODES * sizeof(int), stream);
  hist_kernel<<<(N_EDGES + 255) / 256, 256, 0, stream>>>(dst, cnt, N_EDGES);
  scan_kernel<<<1, 1024, 0, stream>>>(cnt, offs, N_NODES);
  scatter_kernel<<<(N_EDGES + 255) / 256, 256, 0, stream>>>(dst, offs, cursor, elist, N_EDGES);

  const int MB = (N_NODES + BM - 1) / BM;   // 157
  dim3 tb(32, 8);

  for (int l = 0; l < NLAYER; ++l) {
    const float* x_in = (l == 0) ? x0 : xout;
    // ---- weight transpose/cast for this layer (buffers reused across layers) ----
    transpose_cast_kernel<<<dim3(16, 16), tb, 0, stream>>>(Wq + l * S1, wq, 512, 512);
    transpose_cast_kernel<<<dim3(16, 16), tb, 0, stream>>>(Wk + l * S1, wk, 512, 512);
    transpose_cast_kernel<<<dim3(16, 16), tb, 0, stream>>>(Wv + l * S1, wv, 512, 512);
    transpose_cast_kernel<<<dim3(16, 16), tb, 0, stream>>>(Wo + l * S1, wo, 512, 512);
    transpose_cast_kernel<<<dim3(64, 16), tb, 0, stream>>>(W1 + l * S2, w1, 512, 2048);
    transpose_cast_kernel<<<dim3(16, 64), tb, 0, stream>>>(W2 + l * S2, w2, 2048, 512);
    // ---- QKV projections (fp32 A -> bf16 out) ----
    gemm_kernel<false, true><<<dim3(MB, 4), 256, 0, stream>>>(x_in, wq, bq + l * 512, qb, N_NODES, 512, 512, 0);
    gemm_kernel<false, true><<<dim3(MB, 4), 256, 0, stream>>>(x_in, wk, bk + l * 512, kb, N_NODES, 512, 512, 0);
    gemm_kernel<false, true><<<dim3(MB, 4), 256, 0, stream>>>(x_in, wv, bv + l * 512, vb, N_NODES, 512, 512, 0);
    // ---- edge scores + aggregation ----
    score_kernel<<<N_EDGES / 4, 256, 0, stream>>>(qb, kb, rel_embed, relations, src, dst, score, N_EDGES);
    aggregate_kernel<<<N_NODES / 4, 256, 0, stream>>>(score, vb, rel_embed, relations, src, offs, elist, ob, N_NODES);
    // ---- output projection (bf16 A -> fp32 out) + LN1 ----
    gemm_kernel<true, false><<<dim3(MB, 4), 256, 0, stream>>>(ob, wo, bo + l * 512, proj, N_NODES, 512, 512, 0);
    ln_kernel<<<N_NODES / 4, 256, 0, stream>>>(x_in, proj, g1 + l * 512, bb1 + l * 512, hb, N_NODES);
    // ---- FFN: fp32 hb -> bf16 ff1 (relu); bf16 ff1 -> fp32 proj ----
    gemm_kernel<false, true><<<dim3(MB, 16), 256, 0, stream>>>(hb, w1, b1 + l * 2048, ff1, N_NODES, 512, 2048, 1);
    gemm_kernel<true, false><<<dim3(MB, 4), 256, 0, stream>>>(ff1, w2, b2 + l * 512, proj, N_NODES, 2048, 512, 0);
    ln_kernel<<<N_NODES / 4, 256, 0, stream>>>(hb, proj, g2 + l * 512, bb2 + l * 512, xout, N_NODES);
  }
}

// Round 3
// 2232.298 us; speedup vs baseline: 1.2317x; 1.2317x over previous
//
#include <hip/hip_runtime.h>
#include <cstdint>
#include <cstddef>

// ---------------- problem constants ----------------
#define N_NODES 20000
#define N_EDGES 160000
#define HIDDEN  512
#define NHEAD   8
#define HDK     64
#define NLAYER  4
#define FFDIM   2048
#define ATT_SCALE 0.125f   // 1/sqrt(64)

// ---------------- MFMA types ----------------
typedef float  f4  __attribute__((ext_vector_type(4)));
typedef short  s8v __attribute__((ext_vector_type(8)));
typedef __bf16 b8v __attribute__((ext_vector_type(8)));

template <typename V>
__device__ inline auto mfma_try(V a, V b, f4 c, int)
    -> decltype(__builtin_amdgcn_mfma_f32_16x16x32_bf16(a, b, c, 0, 0, 0)) {
  return __builtin_amdgcn_mfma_f32_16x16x32_bf16(a, b, c, 0, 0, 0);
}
template <typename V>
__device__ inline f4 mfma_try(V a, V b, f4 c, long) {
  return __builtin_amdgcn_mfma_f32_16x16x32_bf16(
      __builtin_bit_cast(b8v, a), __builtin_bit_cast(b8v, b), c, 0, 0, 0);
}
__device__ inline f4 mfma_bf16(s8v a, s8v b, f4 c) { return mfma_try(a, b, c, 0); }

__device__ __forceinline__ unsigned short f2bf(float f) {
  unsigned u = __builtin_bit_cast(unsigned, f);
  u += 0x7FFFu + ((u >> 16) & 1u);   // RNE
  return (unsigned short)(u >> 16);
}
__device__ __forceinline__ float bf2f(unsigned short u) {
  return __builtin_bit_cast(float, (unsigned)u << 16);
}

// async global->LDS, 16B per lane; LDS dest is wave-uniform base + lane*16
#define GLOAD_LDS16(gp, lp)                                                   \
  __builtin_amdgcn_global_load_lds(                                           \
      (const __attribute__((address_space(1))) void*)(gp),                    \
      (__attribute__((address_space(3))) void*)(lp), 16, 0, 0)

// ---------------- weight transpose + bf16 cast: in (K x N) fp32 -> out (N x K) bf16 ----------------
__global__ void transpose_cast_kernel(const float* __restrict__ in,
                                      unsigned short* __restrict__ out,
                                      int K, int N) {
  __shared__ float t[32][33];
  int tx = threadIdx.x, ty = threadIdx.y;
  int n0 = blockIdx.x * 32, k0 = blockIdx.y * 32;
#pragma unroll
  for (int i = 0; i < 32; i += 8)
    t[ty + i][tx] = in[(size_t)(k0 + ty + i) * N + n0 + tx];
  __syncthreads();
#pragma unroll
  for (int i = 0; i < 32; i += 8)
    out[(size_t)(n0 + ty + i) * K + k0 + tx] = f2bf(t[tx][ty + i]);
}

// ---------------- fp32 -> bf16 cast ----------------
__global__ void cast_kernel(const float* __restrict__ in, unsigned short* __restrict__ out, int n) {
  int i = blockIdx.x * blockDim.x + threadIdx.x;
  if (i < n) out[i] = f2bf(in[i]);
}

// ---------------- GEMM: C[M,N] = A[M,K] @ Bt[N,K]^T + bias, optional relu ----------------
// A bf16 row-major, Bt bf16 pre-transposed weight. grid.x = N-blocks (fast-varying
// for L2 reuse of A m-stripe + weights), grid.y = M-blocks.
#define BM 128
#define BN 128
#define BK 32
// LDS layout unpadded (global_load_lds constraint): elem = row*32 + col

template <bool OBF16>
__global__ __launch_bounds__(256) void gemm_bf16(
    const unsigned short* __restrict__ A, const unsigned short* __restrict__ Bt,
    const float* __restrict__ bias, void* __restrict__ Cp,
    int M, int K, int N, int relu) {
  __shared__ __align__(16) unsigned short As[BM * BK];
  __shared__ __align__(16) unsigned short Bs[BN * BK];
  int tid = threadIdx.x;
  int wave = tid >> 6, lane = tid & 63;
  int quad = lane >> 4, l16 = lane & 15;
  int wm = (wave >> 1) * 64, wn = (wave & 1) * 64;
  int m0 = blockIdx.y * BM, n0 = blockIdx.x * BN;

  f4 acc[4][4];
#pragma unroll
  for (int i = 0; i < 4; ++i)
#pragma unroll
    for (int j = 0; j < 4; ++j) acc[i][j] = (f4){0.f, 0.f, 0.f, 0.f};

  // staging coords: chunk r covers rows [r*64, r*64+64), thread -> row tid>>2, col (tid&3)*8
  int srow = tid >> 2;
  int scol = (tid & 3) * 8;
  int gma0 = m0 + srow;      if (gma0 >= M) gma0 = M - 1;   // clamp: tail rows duplicate, never stored
  int gma1 = m0 + srow + 64; if (gma1 >= M) gma1 = M - 1;
  const unsigned short* a0 = A + (size_t)gma0 * K + scol;
  const unsigned short* a1 = A + (size_t)gma1 * K + scol;
  const unsigned short* b0 = Bt + (size_t)(n0 + srow) * K + scol;
  const unsigned short* b1 = Bt + (size_t)(n0 + srow + 64) * K + scol;
  unsigned short* lA0 = &As[wave * 512];
  unsigned short* lA1 = &As[2048 + wave * 512];
  unsigned short* lB0 = &Bs[wave * 512];
  unsigned short* lB1 = &Bs[2048 + wave * 512];

  int nk = K >> 5;
  for (int ks = 0; ks < nk; ++ks) {
    GLOAD_LDS16(a0, lA0);
    GLOAD_LDS16(a1, lA1);
    GLOAD_LDS16(b0, lB0);
    GLOAD_LDS16(b1, lB1);
    a0 += BK; a1 += BK; b0 += BK; b1 += BK;
    __syncthreads();
    s8v af[4], bfr[4];
#pragma unroll
    for (int i = 0; i < 4; ++i) {
      af[i]  = *(const s8v*)(&As[(wm + i * 16 + l16) * BK + quad * 8]);
      bfr[i] = *(const s8v*)(&Bs[(wn + i * 16 + l16) * BK + quad * 8]);
    }
#pragma unroll
    for (int mi = 0; mi < 4; ++mi)
#pragma unroll
      for (int ni = 0; ni < 4; ++ni)
        acc[mi][ni] = mfma_bf16(af[mi], bfr[ni], acc[mi][ni]);
    __syncthreads();
  }
  // epilogue: D[row=(lane>>4)*4+r][col=lane&15]
#pragma unroll
  for (int ni = 0; ni < 4; ++ni) {
    int col = n0 + wn + ni * 16 + l16;
    float bv = bias[col];
#pragma unroll
    for (int mi = 0; mi < 4; ++mi) {
#pragma unroll
      for (int r = 0; r < 4; ++r) {
        int row = m0 + wm + mi * 16 + quad * 4 + r;
        if (row < M) {
          float val = acc[mi][ni][r] + bv;
          if (relu) val = fmaxf(val, 0.f);
          if constexpr (OBF16)
            ((unsigned short*)Cp)[(size_t)row * N + col] = f2bf(val);
          else
            ((float*)Cp)[(size_t)row * N + col] = val;
        }
      }
    }
  }
}

// ---------------- CSR build ----------------
__global__ void hist_kernel(const int* __restrict__ dst, int* __restrict__ cnt, int E) {
  int e = blockIdx.x * blockDim.x + threadIdx.x;
  if (e < E) atomicAdd(&cnt[dst[e]], 1);
}

__global__ void scan_kernel(const int* __restrict__ cnt, int* __restrict__ offs, int n) {
  __shared__ int sh[1024];
  __shared__ int carry_sh;
  int tid = threadIdx.x;
  if (tid == 0) carry_sh = 0;
  __syncthreads();
  for (int base = 0; base < n; base += 1024) {
    int v = (base + tid < n) ? cnt[base + tid] : 0;
    sh[tid] = v;
    __syncthreads();
    for (int s = 1; s < 1024; s <<= 1) {
      int t = (tid >= s) ? sh[tid - s] : 0;
      __syncthreads();
      sh[tid] += t;
      __syncthreads();
    }
    int carry = carry_sh;
    if (base + tid < n) offs[base + tid] = carry + sh[tid] - v;
    __syncthreads();
    if (tid == 1023) carry_sh = carry + sh[1023];
    __syncthreads();
  }
  if (tid == 0) offs[n] = carry_sh;
}

__global__ void scatter_kernel(const int* __restrict__ dst, const int* __restrict__ offs,
                               int* __restrict__ cursor, int* __restrict__ elist, int E) {
  int e = blockIdx.x * blockDim.x + threadIdx.x;
  if (e < E) {
    int d = dst[e];
    int pos = offs[d] + atomicAdd(&cursor[d], 1);
    elist[pos] = e;
  }
}

// ---------------- edge scores: score[e][h] = SCALE * dot(k[src]+rh, q[dst]) ----------------
__global__ void score_kernel(const unsigned short* __restrict__ q,
                             const unsigned short* __restrict__ k,
                             const float* __restrict__ rel, const int* __restrict__ relations,
                             const int* __restrict__ src, const int* __restrict__ dst,
                             float* __restrict__ score, int E) {
  int wid = (blockIdx.x * blockDim.x + threadIdx.x) >> 6;
  int lane = threadIdx.x & 63;
  if (wid >= E) return;
  int s = src[wid], d = dst[wid], r = relations[wid];
  const unsigned short* kr = k + (size_t)s * HIDDEN;
  const unsigned short* qr = q + (size_t)d * HIDDEN;
  const float* rr = rel + (size_t)r * HIDDEN;
#pragma unroll
  for (int h = 0; h < NHEAD; ++h) {
    int idx = h * HDK + lane;
    float p = (bf2f(kr[idx]) + rr[idx]) * bf2f(qr[idx]);
#pragma unroll
    for (int off = 32; off; off >>= 1) p += __shfl_xor(p, off, 64);
    if (lane == 0) score[(size_t)wid * NHEAD + h] = p * ATT_SCALE;
  }
}

// ---------------- per-dst softmax + weighted V aggregation (one wave per node) ----------------
__global__ void aggregate_kernel(const float* __restrict__ score,
                                 const unsigned short* __restrict__ v,
                                 const float* __restrict__ rel, const int* __restrict__ relations,
                                 const int* __restrict__ src, const int* __restrict__ offs,
                                 const int* __restrict__ elist,
                                 unsigned short* __restrict__ o, int Nn) {
  int wid = (blockIdx.x * blockDim.x + threadIdx.x) >> 6;
  int lane = threadIdx.x & 63;
  if (wid >= Nn) return;
  int beg = offs[wid], end = offs[wid + 1];
  float m[NHEAD], z[NHEAD], acc[NHEAD];
#pragma unroll
  for (int h = 0; h < NHEAD; ++h) { m[h] = -1e30f; z[h] = 0.f; acc[h] = 0.f; }
  for (int i = beg + lane; i < end; i += 64) {
    int e = elist[i];
#pragma unroll
    for (int h = 0; h < NHEAD; ++h) m[h] = fmaxf(m[h], score[(size_t)e * NHEAD + h]);
  }
#pragma unroll
  for (int h = 0; h < NHEAD; ++h)
#pragma unroll
    for (int off = 32; off; off >>= 1) m[h] = fmaxf(m[h], __shfl_xor(m[h], off, 64));
  for (int i = beg + lane; i < end; i += 64) {
    int e = elist[i];
#pragma unroll
    for (int h = 0; h < NHEAD; ++h) z[h] += __expf(score[(size_t)e * NHEAD + h] - m[h]);
  }
#pragma unroll
  for (int h = 0; h < NHEAD; ++h)
#pragma unroll
    for (int off = 32; off; off >>= 1) z[h] += __shfl_xor(z[h], off, 64);
  for (int i = beg; i < end; ++i) {
    int e = elist[i];
    int s = src[e], r = relations[e];
    const unsigned short* vr = v + (size_t)s * HIDDEN;
    const float* rr = rel + (size_t)r * HIDDEN;
#pragma unroll
    for (int h = 0; h < NHEAD; ++h) {
      float w = __expf(score[(size_t)e * NHEAD + h] - m[h]);
      acc[h] += w * (bf2f(vr[h * HDK + lane]) + rr[h * HDK + lane]);
    }
  }
#pragma unroll
  for (int h = 0; h < NHEAD; ++h)
    o[(size_t)wid * HIDDEN + h * HDK + lane] = f2bf(acc[h] / (z[h] + 1e-9f));
}

// ---------------- fused residual add + LayerNorm (one wave per row) ----------------
// XF32: residual x is fp32 (else bf16). WF32: also write fp32 output.
template <bool XF32, bool WF32>
__global__ void ln_kernel(const void* __restrict__ xp, const float* __restrict__ y,
                          const float* __restrict__ g, const float* __restrict__ b,
                          float* __restrict__ outf, unsigned short* __restrict__ outb, int Nn) {
  int wid = (blockIdx.x * blockDim.x + threadIdx.x) >> 6;
  int lane = threadIdx.x & 63;
  if (wid >= Nn) return;
  const float* yr = y + (size_t)wid * HIDDEN;
  float vals[8];
  float sum = 0.f;
#pragma unroll
  for (int j = 0; j < 8; ++j) {
    int idx = j * 64 + lane;
    float xv;
    if constexpr (XF32) xv = ((const float*)xp)[(size_t)wid * HIDDEN + idx];
    else                xv = bf2f(((const unsigned short*)xp)[(size_t)wid * HIDDEN + idx]);
    vals[j] = xv + yr[idx];
    sum += vals[j];
  }
#pragma unroll
  for (int off = 32; off; off >>= 1) sum += __shfl_xor(sum, off, 64);
  float mean = sum * (1.f / 512.f);
  float sq = 0.f;
#pragma unroll
  for (int j = 0; j < 8; ++j) { float d = vals[j] - mean; sq += d * d; }
#pragma unroll
  for (int off = 32; off; off >>= 1) sq += __shfl_xor(sq, off, 64);
  float rstd = rsqrtf(sq * (1.f / 512.f) + 1e-5f);
#pragma unroll
  for (int j = 0; j < 8; ++j) {
    int idx = j * 64 + lane;
    float val = (vals[j] - mean) * rstd * g[idx] + b[idx];
    if constexpr (WF32) outf[(size_t)wid * HIDDEN + idx] = val;
    outb[(size_t)wid * HIDDEN + idx] = f2bf(val);
  }
}

// ---------------- host orchestration ----------------
extern "C" void kernel_launch(void* const* d_in, const int* in_sizes, int n_in,
                              void* d_out, int out_size, void* d_ws, size_t ws_size,
                              hipStream_t stream) {
  const float* x0        = (const float*)d_in[0];
  const int*   relations = (const int*)d_in[1];
  const int*   src       = (const int*)d_in[2];
  const int*   dst       = (const int*)d_in[3];
  const float* rel_embed = (const float*)d_in[4];
  const float* Wq = (const float*)d_in[5];  const float* bq = (const float*)d_in[6];
  const float* Wk = (const float*)d_in[7];  const float* bk = (const float*)d_in[8];
  const float* Wv = (const float*)d_in[9];  const float* bv = (const float*)d_in[10];
  const float* Wo = (const float*)d_in[11]; const float* bo = (const float*)d_in[12];
  const float* W1 = (const float*)d_in[13]; const float* b1 = (const float*)d_in[14];
  const float* W2 = (const float*)d_in[15]; const float* b2 = (const float*)d_in[16];
  const float* g1  = (const float*)d_in[17]; const float* bb1 = (const float*)d_in[18];
  const float* g2  = (const float*)d_in[19]; const float* bb2 = (const float*)d_in[20];
  float* xout = (float*)d_out;

  const size_t S1 = 512 * 512;
  const size_t S2 = 512 * 2048;
  const size_t NH = (size_t)N_NODES * HIDDEN;   // 10,240,000

  // ---- workspace layout (~176 MiB) ----
  unsigned short* wq = (unsigned short*)d_ws;   // per-layer reused weights (bf16)
  unsigned short* wk = wq + S1;
  unsigned short* wv = wk + S1;
  unsigned short* wo = wv + S1;
  unsigned short* w1 = wo + S1;                 // S2
  unsigned short* w2 = w1 + S2;                 // S2
  unsigned short* arena = w2 + S2;              // 4*NH bf16
  unsigned short* qb = arena;
  unsigned short* kb = arena + NH;
  unsigned short* vb = arena + 2 * NH;
  unsigned short* ob = arena + 3 * NH;
  unsigned short* ff1 = arena;                  // full arena (qkv/ob dead by FF1 time)
  float* proj = (float*)arena;                  // NH fp32, aliases qb|kb (dead at Wo time)
  unsigned short* hbb = arena + 4 * NH;         // NH bf16 (LN1 out; live through LN2)
  unsigned short* xb  = hbb + NH;               // NH bf16 (layer input, A for QKV)
  float* projf = (float*)(xb + NH);             // NH fp32 (FF2 out)
  float* score = projf + NH;                    // E*8 fp32
  int* cnt    = (int*)(score + (size_t)N_EDGES * NHEAD);
  int* offs   = cnt + N_NODES;
  int* cursor = offs + N_NODES + 1;
  int* elist  = cursor + N_NODES;

  // ---- CSR build (once per call) ----
  hipMemsetAsync(cnt, 0, N_NODES * sizeof(int), stream);
  hipMemsetAsync(cursor, 0, N_NODES * sizeof(int), stream);
  hist_kernel<<<(N_EDGES + 255) / 256, 256, 0, stream>>>(dst, cnt, N_EDGES);
  scan_kernel<<<1, 1024, 0, stream>>>(cnt, offs, N_NODES);
  scatter_kernel<<<(N_EDGES + 255) / 256, 256, 0, stream>>>(dst, offs, cursor, elist, N_EDGES);

  // ---- layer-0 input cast ----
  cast_kernel<<<(int)((NH + 255) / 256), 256, 0, stream>>>(x0, xb, (int)NH);

  const int MBc = (N_NODES + BM - 1) / BM;   // 157
  dim3 tb(32, 8);

  for (int l = 0; l < NLAYER; ++l) {
    const float* x_in = (l == 0) ? x0 : xout;
    // weight transpose/cast for this layer
    transpose_cast_kernel<<<dim3(16, 16), tb, 0, stream>>>(Wq + l * S1, wq, 512, 512);
    transpose_cast_kernel<<<dim3(16, 16), tb, 0, stream>>>(Wk + l * S1, wk, 512, 512);
    transpose_cast_kernel<<<dim3(16, 16), tb, 0, stream>>>(Wv + l * S1, wv, 512, 512);
    transpose_cast_kernel<<<dim3(16, 16), tb, 0, stream>>>(Wo + l * S1, wo, 512, 512);
    transpose_cast_kernel<<<dim3(64, 16), tb, 0, stream>>>(W1 + l * S2, w1, 512, 2048);
    transpose_cast_kernel<<<dim3(16, 64), tb, 0, stream>>>(W2 + l * S2, w2, 2048, 512);
    // QKV projections (bf16 A -> bf16 out); grid.x = N-blocks (fast) for L2 reuse
    gemm_bf16<true><<<dim3(4, MBc), 256, 0, stream>>>(xb, wq, bq + l * 512, qb, N_NODES, 512, 512, 0);
    gemm_bf16<true><<<dim3(4, MBc), 256, 0, stream>>>(xb, wk, bk + l * 512, kb, N_NODES, 512, 512, 0);
    gemm_bf16<true><<<dim3(4, MBc), 256, 0, stream>>>(xb, wv, bv + l * 512, vb, N_NODES, 512, 512, 0);
    // edge scores + aggregation
    score_kernel<<<N_EDGES / 4, 256, 0, stream>>>(qb, kb, rel_embed, relations, src, dst, score, N_EDGES);
    aggregate_kernel<<<N_NODES / 4, 256, 0, stream>>>(score, vb, rel_embed, relations, src, offs, elist, ob, N_NODES);
    // output projection -> fp32 proj (aliases dead qb|kb), then LN1 -> hbb (bf16)
    gemm_bf16<false><<<dim3(4, MBc), 256, 0, stream>>>(ob, wo, bo + l * 512, proj, N_NODES, 512, 512, 0);
    ln_kernel<true, false><<<N_NODES / 4, 256, 0, stream>>>(x_in, proj, g1 + l * 512, bb1 + l * 512, nullptr, hbb, N_NODES);
    // FFN: hbb -> ff1 (bf16, relu, overwrites whole arena); ff1 -> projf (fp32)
    gemm_bf16<true><<<dim3(16, MBc), 256, 0, stream>>>(hbb, w1, b1 + l * 2048, ff1, N_NODES, 512, 2048, 1);
    gemm_bf16<false><<<dim3(4, MBc), 256, 0, stream>>>(ff1, w2, b2 + l * 512, projf, N_NODES, 2048, 512, 0);
    // LN2 -> xout (fp32, harness output / next residual) + xb (bf16, next-layer A)
    ln_kernel<false, true><<<N_NODES / 4, 256, 0, stream>>>(hbb, projf, g2 + l * 512, bb2 + l * 512, xout, xb, N_NODES);
  }
}

// Round 4
// 1819.231 us; speedup vs baseline: 1.5113x; 1.2271x over previous
//
#include <hip/hip_runtime.h>
#include <cstdint>
#include <cstddef>

// ---------------- problem constants ----------------
#define N_NODES 20000
#define N_EDGES 160000
#define HIDDEN  512
#define NHEAD   8
#define HDK     64
#define NLAYER  4
#define FFDIM   2048
#define ATT_SCALE 0.125f   // 1/sqrt(64)

// ---------------- MFMA types ----------------
typedef float  f4  __attribute__((ext_vector_type(4)));
typedef short  s8v __attribute__((ext_vector_type(8)));
typedef __bf16 b8v __attribute__((ext_vector_type(8)));

template <typename V>
__device__ inline auto mfma_try(V a, V b, f4 c, int)
    -> decltype(__builtin_amdgcn_mfma_f32_16x16x32_bf16(a, b, c, 0, 0, 0)) {
  return __builtin_amdgcn_mfma_f32_16x16x32_bf16(a, b, c, 0, 0, 0);
}
template <typename V>
__device__ inline f4 mfma_try(V a, V b, f4 c, long) {
  return __builtin_amdgcn_mfma_f32_16x16x32_bf16(
      __builtin_bit_cast(b8v, a), __builtin_bit_cast(b8v, b), c, 0, 0, 0);
}
__device__ inline f4 mfma_bf16(s8v a, s8v b, f4 c) { return mfma_try(a, b, c, 0); }

__device__ __forceinline__ unsigned short f2bf(float f) {
  unsigned u = __builtin_bit_cast(unsigned, f);
  u += 0x7FFFu + ((u >> 16) & 1u);   // RNE
  return (unsigned short)(u >> 16);
}
__device__ __forceinline__ float bf2f(unsigned short u) {
  return __builtin_bit_cast(float, (unsigned)u << 16);
}

// async global->LDS, 16B per lane; LDS dest is wave-uniform base + lane*16
#define GLOAD_LDS16(gp, lp)                                                   \
  __builtin_amdgcn_global_load_lds(                                           \
      (const __attribute__((address_space(1))) void*)(gp),                    \
      (__attribute__((address_space(3))) void*)(lp), 16, 0, 0)

// ---------------- weight transpose + bf16 cast: in (K x N) fp32 -> out (N x K) bf16 ----------------
__global__ void transpose_cast_kernel(const float* __restrict__ in,
                                      unsigned short* __restrict__ out,
                                      int K, int N) {
  __shared__ float t[32][33];
  int tx = threadIdx.x, ty = threadIdx.y;
  int n0 = blockIdx.x * 32, k0 = blockIdx.y * 32;
#pragma unroll
  for (int i = 0; i < 32; i += 8)
    t[ty + i][tx] = in[(size_t)(k0 + ty + i) * N + n0 + tx];
  __syncthreads();
#pragma unroll
  for (int i = 0; i < 32; i += 8)
    out[(size_t)(n0 + ty + i) * K + k0 + tx] = f2bf(t[tx][ty + i]);
}

// ---------------- fp32 -> bf16 cast ----------------
__global__ void cast_kernel(const float* __restrict__ in, unsigned short* __restrict__ out, int n) {
  int i = blockIdx.x * blockDim.x + threadIdx.x;
  if (i < n) out[i] = f2bf(in[i]);
}

// ---------------- GEMM: C[M,N] = A[M,K] @ Bt[N,K]^T + bias, optional relu ----------------
#define BM 128
#define BN 128
#define BK 32
// LDS layout unpadded (global_load_lds constraint): elem = row*32 + col

template <bool OBF16>
__global__ __launch_bounds__(256) void gemm_bf16(
    const unsigned short* __restrict__ A, const unsigned short* __restrict__ Bt,
    const float* __restrict__ bias, void* __restrict__ Cp,
    int M, int K, int N, int relu) {
  __shared__ __align__(16) unsigned short As[BM * BK];
  __shared__ __align__(16) unsigned short Bs[BN * BK];
  int tid = threadIdx.x;
  int wave = tid >> 6, lane = tid & 63;
  int quad = lane >> 4, l16 = lane & 15;
  int wm = (wave >> 1) * 64, wn = (wave & 1) * 64;
  int m0 = blockIdx.y * BM, n0 = blockIdx.x * BN;

  f4 acc[4][4];
#pragma unroll
  for (int i = 0; i < 4; ++i)
#pragma unroll
    for (int j = 0; j < 4; ++j) acc[i][j] = (f4){0.f, 0.f, 0.f, 0.f};

  int srow = tid >> 2;
  int scol = (tid & 3) * 8;
  int gma0 = m0 + srow;      if (gma0 >= M) gma0 = M - 1;
  int gma1 = m0 + srow + 64; if (gma1 >= M) gma1 = M - 1;
  const unsigned short* a0 = A + (size_t)gma0 * K + scol;
  const unsigned short* a1 = A + (size_t)gma1 * K + scol;
  const unsigned short* b0 = Bt + (size_t)(n0 + srow) * K + scol;
  const unsigned short* b1 = Bt + (size_t)(n0 + srow + 64) * K + scol;
  unsigned short* lA0 = &As[wave * 512];
  unsigned short* lA1 = &As[2048 + wave * 512];
  unsigned short* lB0 = &Bs[wave * 512];
  unsigned short* lB1 = &Bs[2048 + wave * 512];

  int nk = K >> 5;
  for (int ks = 0; ks < nk; ++ks) {
    GLOAD_LDS16(a0, lA0);
    GLOAD_LDS16(a1, lA1);
    GLOAD_LDS16(b0, lB0);
    GLOAD_LDS16(b1, lB1);
    a0 += BK; a1 += BK; b0 += BK; b1 += BK;
    __syncthreads();
    s8v af[4], bfr[4];
#pragma unroll
    for (int i = 0; i < 4; ++i) {
      af[i]  = *(const s8v*)(&As[(wm + i * 16 + l16) * BK + quad * 8]);
      bfr[i] = *(const s8v*)(&Bs[(wn + i * 16 + l16) * BK + quad * 8]);
    }
#pragma unroll
    for (int mi = 0; mi < 4; ++mi)
#pragma unroll
      for (int ni = 0; ni < 4; ++ni)
        acc[mi][ni] = mfma_bf16(af[mi], bfr[ni], acc[mi][ni]);
    __syncthreads();
  }
#pragma unroll
  for (int ni = 0; ni < 4; ++ni) {
    int col = n0 + wn + ni * 16 + l16;
    float bv = bias[col];
#pragma unroll
    for (int mi = 0; mi < 4; ++mi) {
#pragma unroll
      for (int r = 0; r < 4; ++r) {
        int row = m0 + wm + mi * 16 + quad * 4 + r;
        if (row < M) {
          float val = acc[mi][ni][r] + bv;
          if (relu) val = fmaxf(val, 0.f);
          if constexpr (OBF16)
            ((unsigned short*)Cp)[(size_t)row * N + col] = f2bf(val);
          else
            ((float*)Cp)[(size_t)row * N + col] = val;
        }
      }
    }
  }
}

// ---------------- CSR build ----------------
__global__ void hist_kernel(const int* __restrict__ dst, int* __restrict__ cnt, int E) {
  int e = blockIdx.x * blockDim.x + threadIdx.x;
  if (e < E) atomicAdd(&cnt[dst[e]], 1);
}

__global__ void scan_kernel(const int* __restrict__ cnt, int* __restrict__ offs, int n) {
  __shared__ int sh[1024];
  __shared__ int carry_sh;
  int tid = threadIdx.x;
  if (tid == 0) carry_sh = 0;
  __syncthreads();
  for (int base = 0; base < n; base += 1024) {
    int v = (base + tid < n) ? cnt[base + tid] : 0;
    sh[tid] = v;
    __syncthreads();
    for (int s = 1; s < 1024; s <<= 1) {
      int t = (tid >= s) ? sh[tid - s] : 0;
      __syncthreads();
      sh[tid] += t;
      __syncthreads();
    }
    int carry = carry_sh;
    if (base + tid < n) offs[base + tid] = carry + sh[tid] - v;
    __syncthreads();
    if (tid == 1023) carry_sh = carry + sh[1023];
    __syncthreads();
  }
  if (tid == 0) offs[n] = carry_sh;
}

// CSR-ordered companion arrays: esrc[i], erel[i] for pass loops (no indirection chain)
__global__ void scatter_kernel(const int* __restrict__ dst, const int* __restrict__ src,
                               const int* __restrict__ relations, const int* __restrict__ offs,
                               int* __restrict__ cursor, int* __restrict__ esrc,
                               int* __restrict__ erel, int E) {
  int e = blockIdx.x * blockDim.x + threadIdx.x;
  if (e < E) {
    int d = dst[e];
    int pos = offs[d] + atomicAdd(&cursor[d], 1);
    esrc[pos] = src[e];
    erel[pos] = relations[e];
  }
}

// ---------------- fused edge attention: one wave per dst node, online softmax ----------------
// lane = (head h = lane>>3, chunk c = lane&7); lane owns elems [h*64 + c*8, +8)
__global__ void edge_attn_kernel(const unsigned short* __restrict__ q,
                                 const unsigned short* __restrict__ k,
                                 const unsigned short* __restrict__ v,
                                 const float* __restrict__ rel,
                                 const int* __restrict__ offs,
                                 const int* __restrict__ esrc,
                                 const int* __restrict__ erel,
                                 unsigned short* __restrict__ o, int Nn) {
  int wid = (blockIdx.x * blockDim.x + threadIdx.x) >> 6;
  int lane = threadIdx.x & 63;
  if (wid >= Nn) return;
  int base = (lane >> 3) * HDK + (lane & 7) * 8;

  // q row: loaded once per node
  s8v qv = *(const s8v*)(q + (size_t)wid * HIDDEN + base);
  float qf[8];
#pragma unroll
  for (int j = 0; j < 8; ++j) qf[j] = bf2f((unsigned short)qv[j]);

  int beg = offs[wid], end = offs[wid + 1];
  float m = -1e30f, z = 0.f;
  float acc[8];
#pragma unroll
  for (int j = 0; j < 8; ++j) acc[j] = 0.f;

  for (int i = beg; i < end; ++i) {
    int s = esrc[i], r = erel[i];
    s8v kv = *(const s8v*)(k + (size_t)s * HIDDEN + base);
    const float* rr = rel + (size_t)r * HIDDEN + base;
    float4 r0 = *(const float4*)rr;
    float4 r1 = *(const float4*)(rr + 4);
    float rf[8] = {r0.x, r0.y, r0.z, r0.w, r1.x, r1.y, r1.z, r1.w};
    float p = 0.f;
#pragma unroll
    for (int j = 0; j < 8; ++j) p += (bf2f((unsigned short)kv[j]) + rf[j]) * qf[j];
    // butterfly over the 8 lanes of this head: all octet lanes end with the head sum
    p += __shfl_xor(p, 1, 64);
    p += __shfl_xor(p, 2, 64);
    p += __shfl_xor(p, 4, 64);
    p *= ATT_SCALE;
    float mn = fmaxf(m, p);
    float a = __expf(m - mn);    // rescale of old state (0 on first edge)
    float w = __expf(p - mn);
    s8v vv = *(const s8v*)(v + (size_t)s * HIDDEN + base);
    z = z * a + w;
#pragma unroll
    for (int j = 0; j < 8; ++j)
      acc[j] = acc[j] * a + w * (bf2f((unsigned short)vv[j]) + rf[j]);
    m = mn;
  }
  float rz = 1.f / (z + 1e-9f);
  s8v ov;
#pragma unroll
  for (int j = 0; j < 8; ++j) ov[j] = (short)f2bf(acc[j] * rz);
  *(s8v*)(o + (size_t)wid * HIDDEN + base) = ov;
}

// ---------------- fused residual add + LayerNorm (one wave per row) ----------------
template <bool XF32, bool WF32>
__global__ void ln_kernel(const void* __restrict__ xp, const float* __restrict__ y,
                          const float* __restrict__ g, const float* __restrict__ b,
                          float* __restrict__ outf, unsigned short* __restrict__ outb, int Nn) {
  int wid = (blockIdx.x * blockDim.x + threadIdx.x) >> 6;
  int lane = threadIdx.x & 63;
  if (wid >= Nn) return;
  const float* yr = y + (size_t)wid * HIDDEN;
  float vals[8];
  float sum = 0.f;
#pragma unroll
  for (int j = 0; j < 8; ++j) {
    int idx = j * 64 + lane;
    float xv;
    if constexpr (XF32) xv = ((const float*)xp)[(size_t)wid * HIDDEN + idx];
    else                xv = bf2f(((const unsigned short*)xp)[(size_t)wid * HIDDEN + idx]);
    vals[j] = xv + yr[idx];
    sum += vals[j];
  }
#pragma unroll
  for (int off = 32; off; off >>= 1) sum += __shfl_xor(sum, off, 64);
  float mean = sum * (1.f / 512.f);
  float sq = 0.f;
#pragma unroll
  for (int j = 0; j < 8; ++j) { float d = vals[j] - mean; sq += d * d; }
#pragma unroll
  for (int off = 32; off; off >>= 1) sq += __shfl_xor(sq, off, 64);
  float rstd = rsqrtf(sq * (1.f / 512.f) + 1e-5f);
#pragma unroll
  for (int j = 0; j < 8; ++j) {
    int idx = j * 64 + lane;
    float val = (vals[j] - mean) * rstd * g[idx] + b[idx];
    if constexpr (WF32) outf[(size_t)wid * HIDDEN + idx] = val;
    outb[(size_t)wid * HIDDEN + idx] = f2bf(val);
  }
}

// ---------------- host orchestration ----------------
extern "C" void kernel_launch(void* const* d_in, const int* in_sizes, int n_in,
                              void* d_out, int out_size, void* d_ws, size_t ws_size,
                              hipStream_t stream) {
  const float* x0        = (const float*)d_in[0];
  const int*   relations = (const int*)d_in[1];
  const int*   src       = (const int*)d_in[2];
  const int*   dst       = (const int*)d_in[3];
  const float* rel_embed = (const float*)d_in[4];
  const float* Wq = (const float*)d_in[5];  const float* bq = (const float*)d_in[6];
  const float* Wk = (const float*)d_in[7];  const float* bk = (const float*)d_in[8];
  const float* Wv = (const float*)d_in[9];  const float* bv = (const float*)d_in[10];
  const float* Wo = (const float*)d_in[11]; const float* bo = (const float*)d_in[12];
  const float* W1 = (const float*)d_in[13]; const float* b1 = (const float*)d_in[14];
  const float* W2 = (const float*)d_in[15]; const float* b2 = (const float*)d_in[16];
  const float* g1  = (const float*)d_in[17]; const float* bb1 = (const float*)d_in[18];
  const float* g2  = (const float*)d_in[19]; const float* bb2 = (const float*)d_in[20];
  float* xout = (float*)d_out;

  const size_t S1 = 512 * 512;
  const size_t S2 = 512 * 2048;
  const size_t NH = (size_t)N_NODES * HIDDEN;   // 10,240,000

  // ---- workspace layout (~172 MiB) ----
  unsigned short* wq = (unsigned short*)d_ws;   // per-layer reused weights (bf16)
  unsigned short* wk = wq + S1;
  unsigned short* wv = wk + S1;
  unsigned short* wo = wv + S1;
  unsigned short* w1 = wo + S1;                 // S2
  unsigned short* w2 = w1 + S2;                 // S2
  unsigned short* arena = w2 + S2;              // 4*NH bf16
  unsigned short* qb = arena;
  unsigned short* kb = arena + NH;
  unsigned short* vb = arena + 2 * NH;
  unsigned short* ob = arena + 3 * NH;
  unsigned short* ff1 = arena;                  // full arena (qkv/ob dead by FF1 time)
  float* proj = (float*)arena;                  // NH fp32, aliases qb|kb (dead at Wo time)
  unsigned short* hbb = arena + 4 * NH;         // NH bf16 (LN1 out; live through LN2)
  unsigned short* xb  = hbb + NH;               // NH bf16 (layer input, A for QKV)
  float* projf = (float*)(xb + NH);             // NH fp32 (FF2 out)
  int* cnt    = (int*)(projf + NH);
  int* offs   = cnt + N_NODES;
  int* cursor = offs + N_NODES + 1;
  int* esrc   = cursor + N_NODES;
  int* erel   = esrc + N_EDGES;

  // ---- CSR build (once per call) ----
  hipMemsetAsync(cnt, 0, N_NODES * sizeof(int), stream);
  hipMemsetAsync(cursor, 0, N_NODES * sizeof(int), stream);
  hist_kernel<<<(N_EDGES + 255) / 256, 256, 0, stream>>>(dst, cnt, N_EDGES);
  scan_kernel<<<1, 1024, 0, stream>>>(cnt, offs, N_NODES);
  scatter_kernel<<<(N_EDGES + 255) / 256, 256, 0, stream>>>(dst, src, relations, offs, cursor, esrc, erel, N_EDGES);

  // ---- layer-0 input cast ----
  cast_kernel<<<(int)((NH + 255) / 256), 256, 0, stream>>>(x0, xb, (int)NH);

  const int MBc = (N_NODES + BM - 1) / BM;   // 157
  dim3 tb(32, 8);

  for (int l = 0; l < NLAYER; ++l) {
    const float* x_in = (l == 0) ? x0 : xout;
    // weight transpose/cast for this layer
    transpose_cast_kernel<<<dim3(16, 16), tb, 0, stream>>>(Wq + l * S1, wq, 512, 512);
    transpose_cast_kernel<<<dim3(16, 16), tb, 0, stream>>>(Wk + l * S1, wk, 512, 512);
    transpose_cast_kernel<<<dim3(16, 16), tb, 0, stream>>>(Wv + l * S1, wv, 512, 512);
    transpose_cast_kernel<<<dim3(16, 16), tb, 0, stream>>>(Wo + l * S1, wo, 512, 512);
    transpose_cast_kernel<<<dim3(64, 16), tb, 0, stream>>>(W1 + l * S2, w1, 512, 2048);
    transpose_cast_kernel<<<dim3(16, 64), tb, 0, stream>>>(W2 + l * S2, w2, 2048, 512);
    // QKV projections (bf16 A -> bf16 out); grid.x = N-blocks (fast) for L2 reuse
    gemm_bf16<true><<<dim3(4, MBc), 256, 0, stream>>>(xb, wq, bq + l * 512, qb, N_NODES, 512, 512, 0);
    gemm_bf16<true><<<dim3(4, MBc), 256, 0, stream>>>(xb, wk, bk + l * 512, kb, N_NODES, 512, 512, 0);
    gemm_bf16<true><<<dim3(4, MBc), 256, 0, stream>>>(xb, wv, bv + l * 512, vb, N_NODES, 512, 512, 0);
    // fused edge attention (score + online softmax + aggregation)
    edge_attn_kernel<<<(N_NODES + 3) / 4, 256, 0, stream>>>(qb, kb, vb, rel_embed, offs, esrc, erel, ob, N_NODES);
    // output projection -> fp32 proj (aliases dead qb|kb), then LN1 -> hbb (bf16)
    gemm_bf16<false><<<dim3(4, MBc), 256, 0, stream>>>(ob, wo, bo + l * 512, proj, N_NODES, 512, 512, 0);
    ln_kernel<true, false><<<N_NODES / 4, 256, 0, stream>>>(x_in, proj, g1 + l * 512, bb1 + l * 512, nullptr, hbb, N_NODES);
    // FFN: hbb -> ff1 (bf16, relu, overwrites whole arena); ff1 -> projf (fp32)
    gemm_bf16<true><<<dim3(16, MBc), 256, 0, stream>>>(hbb, w1, b1 + l * 2048, ff1, N_NODES, 512, 2048, 1);
    gemm_bf16<false><<<dim3(4, MBc), 256, 0, stream>>>(ff1, w2, b2 + l * 512, projf, N_NODES, 2048, 512, 0);
    // LN2 -> xout (fp32, harness output / next residual) + xb (bf16, next-layer A)
    ln_kernel<false, true><<<N_NODES / 4, 256, 0, stream>>>(hbb, projf, g2 + l * 512, bb2 + l * 512, xout, xb, N_NODES);
  }
}

// Round 5
// 1567.754 us; speedup vs baseline: 1.7538x; 1.1604x over previous
//
#include <hip/hip_runtime.h>
#include <cstdint>
#include <cstddef>

// ---------------- problem constants ----------------
#define N_NODES 20000
#define N_EDGES 160000
#define HIDDEN  512
#define NHEAD   8
#define HDK     64
#define NLAYER  4
#define FFDIM   2048
#define ATT_SCALE 0.125f   // 1/sqrt(64)

// ---------------- MFMA types ----------------
typedef float  f4  __attribute__((ext_vector_type(4)));
typedef short  s8v __attribute__((ext_vector_type(8)));
typedef __bf16 b8v __attribute__((ext_vector_type(8)));

template <typename V>
__device__ inline auto mfma_try(V a, V b, f4 c, int)
    -> decltype(__builtin_amdgcn_mfma_f32_16x16x32_bf16(a, b, c, 0, 0, 0)) {
  return __builtin_amdgcn_mfma_f32_16x16x32_bf16(a, b, c, 0, 0, 0);
}
template <typename V>
__device__ inline f4 mfma_try(V a, V b, f4 c, long) {
  return __builtin_amdgcn_mfma_f32_16x16x32_bf16(
      __builtin_bit_cast(b8v, a), __builtin_bit_cast(b8v, b), c, 0, 0, 0);
}
__device__ inline f4 mfma_bf16(s8v a, s8v b, f4 c) { return mfma_try(a, b, c, 0); }

__device__ __forceinline__ unsigned short f2bf(float f) {
  unsigned u = __builtin_bit_cast(unsigned, f);
  u += 0x7FFFu + ((u >> 16) & 1u);   // RNE
  return (unsigned short)(u >> 16);
}
__device__ __forceinline__ float bf2f(unsigned short u) {
  return __builtin_bit_cast(float, (unsigned)u << 16);
}

// async global->LDS, 16B per lane; LDS dest is wave-uniform base + lane*16
#define GLOAD_LDS16(gp, lp)                                                   \
  __builtin_amdgcn_global_load_lds(                                           \
      (const __attribute__((address_space(1))) void*)(gp),                    \
      (__attribute__((address_space(3))) void*)(lp), 16, 0, 0)

// ---------------- weight transpose + bf16 cast: in (K x N) fp32 -> out (N x K) bf16 ----------------
__global__ void transpose_cast_kernel(const float* __restrict__ in,
                                      unsigned short* __restrict__ out,
                                      int K, int N) {
  __shared__ float t[32][33];
  int tx = threadIdx.x, ty = threadIdx.y;
  int n0 = blockIdx.x * 32, k0 = blockIdx.y * 32;
#pragma unroll
  for (int i = 0; i < 32; i += 8)
    t[ty + i][tx] = in[(size_t)(k0 + ty + i) * N + n0 + tx];
  __syncthreads();
#pragma unroll
  for (int i = 0; i < 32; i += 8)
    out[(size_t)(n0 + ty + i) * K + k0 + tx] = f2bf(t[tx][ty + i]);
}

// ---------------- fp32 -> bf16 cast ----------------
__global__ void cast_kernel(const float* __restrict__ in, unsigned short* __restrict__ out, int n) {
  int i = blockIdx.x * blockDim.x + threadIdx.x;
  if (i < n) out[i] = f2bf(in[i]);
}

// ---------------- bias concat: [bq | bk | bv] -> 1536 ----------------
__global__ void bias_concat_kernel(const float* __restrict__ a, const float* __restrict__ b,
                                   const float* __restrict__ c, float* __restrict__ out) {
  int i = threadIdx.x + blockIdx.x * blockDim.x;
  if (i < 512) out[i] = a[i];
  else if (i < 1024) out[i] = b[i - 512];
  else if (i < 1536) out[i] = c[i - 1024];
}

// ---------------- GEMM: C[M,N] = A[M,K] @ Bt[N,K]^T + bias, optional relu ----------------
// XOR-swizzled LDS: global chunk (row, q) stored at chunk (row, q ^ ((row>>1)&3)).
#define BM 128
#define BN 128
#define BK 32

template <bool OBF16>
__global__ __launch_bounds__(256) void gemm_bf16(
    const unsigned short* __restrict__ A, const unsigned short* __restrict__ Bt,
    const float* __restrict__ bias, void* __restrict__ Cp,
    int M, int K, int N, int relu) {
  __shared__ __align__(16) unsigned short smem[8192];   // As: [0,4096) Bs: [4096,8192)
  unsigned short* As = smem;
  unsigned short* Bs = smem + 4096;
  int tid = threadIdx.x;
  int wave = tid >> 6, lane = tid & 63;
  int quad = lane >> 4, l16 = lane & 15;
  int wm = (wave >> 1) * 64, wn = (wave & 1) * 64;
  int m0 = blockIdx.y * BM, n0 = blockIdx.x * BN;

  f4 acc[4][4];
#pragma unroll
  for (int i = 0; i < 4; ++i)
#pragma unroll
    for (int j = 0; j < 4; ++j) acc[i][j] = (f4){0.f, 0.f, 0.f, 0.f};

  // staging: LDS chunk index == tid (per 64-row half); global col chunk is XOR-swizzled
  int srow = tid >> 2;                              // 0..63
  int qs   = tid & 3;
  int scol = (qs ^ ((srow >> 1) & 3)) * 8;          // swizzled 8-elem chunk
  int gma0 = m0 + srow;      if (gma0 >= M) gma0 = M - 1;   // clamp: dup rows never stored
  int gma1 = m0 + srow + 64; if (gma1 >= M) gma1 = M - 1;
  const unsigned short* a0 = A + (size_t)gma0 * K + scol;
  const unsigned short* a1 = A + (size_t)gma1 * K + scol;
  const unsigned short* b0 = Bt + (size_t)(n0 + srow) * K + scol;
  const unsigned short* b1 = Bt + (size_t)(n0 + srow + 64) * K + scol;
  unsigned short* lA0 = &As[wave * 512];
  unsigned short* lA1 = &As[2048 + wave * 512];
  unsigned short* lB0 = &Bs[wave * 512];
  unsigned short* lB1 = &Bs[2048 + wave * 512];

  int nk = K >> 5;
  for (int ks = 0; ks < nk; ++ks) {
    GLOAD_LDS16(a0, lA0);
    GLOAD_LDS16(a1, lA1);
    GLOAD_LDS16(b0, lB0);
    GLOAD_LDS16(b1, lB1);
    a0 += BK; a1 += BK; b0 += BK; b1 += BK;
    __syncthreads();
    s8v af[4], bfr[4];
#pragma unroll
    for (int i = 0; i < 4; ++i) {
      int ra = wm + i * 16 + l16;
      int rb = wn + i * 16 + l16;
      af[i]  = *(const s8v*)(&As[ra * BK + ((quad ^ ((ra >> 1) & 3)) * 8)]);
      bfr[i] = *(const s8v*)(&Bs[rb * BK + ((quad ^ ((rb >> 1) & 3)) * 8)]);
    }
#pragma unroll
    for (int mi = 0; mi < 4; ++mi)
#pragma unroll
      for (int ni = 0; ni < 4; ++ni)
        acc[mi][ni] = mfma_bf16(af[mi], bfr[ni], acc[mi][ni]);
    __syncthreads();
  }

  if constexpr (OBF16) {
    // coalesced bf16 epilogue: restage each wave's 16x64 subtile through LDS
    unsigned short* Cs = smem + wave * 1088;   // 16 rows x 64 cols, stride 68 (bank-spread)
    float bvv[4];
#pragma unroll
    for (int ni = 0; ni < 4; ++ni) bvv[ni] = bias[n0 + wn + ni * 16 + l16];
    int row_l = lane >> 2, cg = lane & 3;
#pragma unroll
    for (int mi = 0; mi < 4; ++mi) {
#pragma unroll
      for (int ni = 0; ni < 4; ++ni) {
#pragma unroll
        for (int r = 0; r < 4; ++r) {
          float val = acc[mi][ni][r] + bvv[ni];
          if (relu) val = fmaxf(val, 0.f);
          Cs[(quad * 4 + r) * 68 + ni * 16 + l16] = f2bf(val);
        }
      }
      s8v v0 = *(const s8v*)(&Cs[row_l * 68 + cg * 16]);
      s8v v1 = *(const s8v*)(&Cs[row_l * 68 + cg * 16 + 8]);
      int grow = m0 + wm + mi * 16 + row_l;
      if (grow < M) {
        unsigned short* cp = (unsigned short*)Cp + (size_t)grow * N + n0 + wn + cg * 16;
        *(s8v*)cp = v0;
        *(s8v*)(cp + 8) = v1;
      }
    }
  } else {
    // fp32 epilogue: 16 lanes x 4B = 64B contiguous per row segment — already coalesced
#pragma unroll
    for (int ni = 0; ni < 4; ++ni) {
      int col = n0 + wn + ni * 16 + l16;
      float bv = bias[col];
#pragma unroll
      for (int mi = 0; mi < 4; ++mi) {
#pragma unroll
        for (int r = 0; r < 4; ++r) {
          int row = m0 + wm + mi * 16 + quad * 4 + r;
          if (row < M) {
            float val = acc[mi][ni][r] + bv;
            if (relu) val = fmaxf(val, 0.f);
            ((float*)Cp)[(size_t)row * N + col] = val;
          }
        }
      }
    }
  }
}

// ---------------- CSR build ----------------
__global__ void hist_kernel(const int* __restrict__ dst, int* __restrict__ cnt, int E) {
  int e = blockIdx.x * blockDim.x + threadIdx.x;
  if (e < E) atomicAdd(&cnt[dst[e]], 1);
}

__global__ void scan_kernel(const int* __restrict__ cnt, int* __restrict__ offs, int n) {
  __shared__ int sh[1024];
  __shared__ int carry_sh;
  int tid = threadIdx.x;
  if (tid == 0) carry_sh = 0;
  __syncthreads();
  for (int base = 0; base < n; base += 1024) {
    int v = (base + tid < n) ? cnt[base + tid] : 0;
    sh[tid] = v;
    __syncthreads();
    for (int s = 1; s < 1024; s <<= 1) {
      int t = (tid >= s) ? sh[tid - s] : 0;
      __syncthreads();
      sh[tid] += t;
      __syncthreads();
    }
    int carry = carry_sh;
    if (base + tid < n) offs[base + tid] = carry + sh[tid] - v;
    __syncthreads();
    if (tid == 1023) carry_sh = carry + sh[1023];
    __syncthreads();
  }
  if (tid == 0) offs[n] = carry_sh;
}

__global__ void scatter_kernel(const int* __restrict__ dst, const int* __restrict__ src,
                               const int* __restrict__ relations, const int* __restrict__ offs,
                               int* __restrict__ cursor, int* __restrict__ esrc,
                               int* __restrict__ erel, int E) {
  int e = blockIdx.x * blockDim.x + threadIdx.x;
  if (e < E) {
    int d = dst[e];
    int pos = offs[d] + atomicAdd(&cursor[d], 1);
    esrc[pos] = src[e];
    erel[pos] = relations[e];
  }
}

// ---------------- fused edge attention: one wave per dst node, online softmax ----------------
// lane = (head h = lane>>3, chunk c = lane&7); lane owns elems [h*64 + c*8, +8)
// q/k/v row stride = STR (merged qkv buffer)
__global__ void edge_attn_kernel(const unsigned short* __restrict__ q,
                                 const unsigned short* __restrict__ k,
                                 const unsigned short* __restrict__ v,
                                 const float* __restrict__ rel,
                                 const int* __restrict__ offs,
                                 const int* __restrict__ esrc,
                                 const int* __restrict__ erel,
                                 unsigned short* __restrict__ o, int Nn, int STR) {
  int wid = (blockIdx.x * blockDim.x + threadIdx.x) >> 6;
  int lane = threadIdx.x & 63;
  if (wid >= Nn) return;
  int base = (lane >> 3) * HDK + (lane & 7) * 8;

  s8v qv = *(const s8v*)(q + (size_t)wid * STR + base);
  float qf[8];
#pragma unroll
  for (int j = 0; j < 8; ++j) qf[j] = bf2f((unsigned short)qv[j]);

  int beg = offs[wid], end = offs[wid + 1];
  float m = -1e30f, z = 0.f;
  float acc[8];
#pragma unroll
  for (int j = 0; j < 8; ++j) acc[j] = 0.f;

  for (int i = beg; i < end; ++i) {
    int s = esrc[i], r = erel[i];
    s8v kv = *(const s8v*)(k + (size_t)s * STR + base);
    const float* rr = rel + (size_t)r * HIDDEN + base;
    float4 r0 = *(const float4*)rr;
    float4 r1 = *(const float4*)(rr + 4);
    float rf[8] = {r0.x, r0.y, r0.z, r0.w, r1.x, r1.y, r1.z, r1.w};
    float p = 0.f;
#pragma unroll
    for (int j = 0; j < 8; ++j) p += (bf2f((unsigned short)kv[j]) + rf[j]) * qf[j];
    p += __shfl_xor(p, 1, 64);
    p += __shfl_xor(p, 2, 64);
    p += __shfl_xor(p, 4, 64);
    p *= ATT_SCALE;
    float mn = fmaxf(m, p);
    float a = __expf(m - mn);
    float w = __expf(p - mn);
    s8v vv = *(const s8v*)(v + (size_t)s * STR + base);
    z = z * a + w;
#pragma unroll
    for (int j = 0; j < 8; ++j)
      acc[j] = acc[j] * a + w * (bf2f((unsigned short)vv[j]) + rf[j]);
    m = mn;
  }
  float rz = 1.f / (z + 1e-9f);
  s8v ov;
#pragma unroll
  for (int j = 0; j < 8; ++j) ov[j] = (short)f2bf(acc[j] * rz);
  *(s8v*)(o + (size_t)wid * HIDDEN + base) = ov;
}

// ---------------- fused residual add + LayerNorm (one wave per row) ----------------
template <bool XF32, bool WF32>
__global__ void ln_kernel(const void* __restrict__ xp, const float* __restrict__ y,
                          const float* __restrict__ g, const float* __restrict__ b,
                          float* __restrict__ outf, unsigned short* __restrict__ outb, int Nn) {
  int wid = (blockIdx.x * blockDim.x + threadIdx.x) >> 6;
  int lane = threadIdx.x & 63;
  if (wid >= Nn) return;
  const float* yr = y + (size_t)wid * HIDDEN;
  float vals[8];
  float sum = 0.f;
#pragma unroll
  for (int j = 0; j < 8; ++j) {
    int idx = j * 64 + lane;
    float xv;
    if constexpr (XF32) xv = ((const float*)xp)[(size_t)wid * HIDDEN + idx];
    else                xv = bf2f(((const unsigned short*)xp)[(size_t)wid * HIDDEN + idx]);
    vals[j] = xv + yr[idx];
    sum += vals[j];
  }
#pragma unroll
  for (int off = 32; off; off >>= 1) sum += __shfl_xor(sum, off, 64);
  float mean = sum * (1.f / 512.f);
  float sq = 0.f;
#pragma unroll
  for (int j = 0; j < 8; ++j) { float d = vals[j] - mean; sq += d * d; }
#pragma unroll
  for (int off = 32; off; off >>= 1) sq += __shfl_xor(sq, off, 64);
  float rstd = rsqrtf(sq * (1.f / 512.f) + 1e-5f);
#pragma unroll
  for (int j = 0; j < 8; ++j) {
    int idx = j * 64 + lane;
    float val = (vals[j] - mean) * rstd * g[idx] + b[idx];
    if constexpr (WF32) outf[(size_t)wid * HIDDEN + idx] = val;
    outb[(size_t)wid * HIDDEN + idx] = f2bf(val);
  }
}

// ---------------- host orchestration ----------------
extern "C" void kernel_launch(void* const* d_in, const int* in_sizes, int n_in,
                              void* d_out, int out_size, void* d_ws, size_t ws_size,
                              hipStream_t stream) {
  const float* x0        = (const float*)d_in[0];
  const int*   relations = (const int*)d_in[1];
  const int*   src       = (const int*)d_in[2];
  const int*   dst       = (const int*)d_in[3];
  const float* rel_embed = (const float*)d_in[4];
  const float* Wq = (const float*)d_in[5];  const float* bq = (const float*)d_in[6];
  const float* Wk = (const float*)d_in[7];  const float* bk = (const float*)d_in[8];
  const float* Wv = (const float*)d_in[9];  const float* bv = (const float*)d_in[10];
  const float* Wo = (const float*)d_in[11]; const float* bo = (const float*)d_in[12];
  const float* W1 = (const float*)d_in[13]; const float* b1 = (const float*)d_in[14];
  const float* W2 = (const float*)d_in[15]; const float* b2 = (const float*)d_in[16];
  const float* g1  = (const float*)d_in[17]; const float* bb1 = (const float*)d_in[18];
  const float* g2  = (const float*)d_in[19]; const float* bb2 = (const float*)d_in[20];
  float* xout = (float*)d_out;

  const size_t S1 = 512 * 512;
  const size_t S2 = 512 * 2048;
  const size_t NH = (size_t)N_NODES * HIDDEN;   // 10,240,000

  // ---- workspace layout (~172 MiB) ----
  unsigned short* wqkv = (unsigned short*)d_ws; // 3*S1 (rows 0-511 q, 512-1023 k, 1024-1535 v)
  unsigned short* wo = wqkv + 3 * S1;
  unsigned short* w1 = wo + S1;                 // S2
  unsigned short* w2 = w1 + S2;                 // S2
  float* bqkv = (float*)(w2 + S2);              // 1536 fp32 concat bias
  unsigned short* arena = (unsigned short*)(bqkv + 1536);  // 4*NH bf16
  unsigned short* qkvb = arena;                 // 3*NH, row stride 1536
  unsigned short* ob   = arena + 3 * NH;        // NH, row stride 512
  unsigned short* ff1  = arena;                 // 4*NH (qkv+ob dead by FF1 time)
  float* proj = (float*)arena;                  // NH fp32, aliases qkvb (dead at Wo time)
  unsigned short* hbb = arena + 4 * NH;         // NH bf16 (LN1 out)
  unsigned short* xb  = hbb + NH;               // NH bf16 (layer input)
  float* projf = (float*)(xb + NH);             // NH fp32 (FF2 out)
  int* cnt    = (int*)(projf + NH);
  int* offs   = cnt + N_NODES;
  int* cursor = offs + N_NODES + 1;
  int* esrc   = cursor + N_NODES;
  int* erel   = esrc + N_EDGES;

  // ---- CSR build (once per call) ----
  hipMemsetAsync(cnt, 0, N_NODES * sizeof(int), stream);
  hipMemsetAsync(cursor, 0, N_NODES * sizeof(int), stream);
  hist_kernel<<<(N_EDGES + 255) / 256, 256, 0, stream>>>(dst, cnt, N_EDGES);
  scan_kernel<<<1, 1024, 0, stream>>>(cnt, offs, N_NODES);
  scatter_kernel<<<(N_EDGES + 255) / 256, 256, 0, stream>>>(dst, src, relations, offs, cursor, esrc, erel, N_EDGES);

  // ---- layer-0 input cast ----
  cast_kernel<<<(int)((NH + 255) / 256), 256, 0, stream>>>(x0, xb, (int)NH);

  const int MBc = (N_NODES + BM - 1) / BM;   // 157
  dim3 tb(32, 8);

  for (int l = 0; l < NLAYER; ++l) {
    const float* x_in = (l == 0) ? x0 : xout;
    // weight transpose/cast for this layer (q/k/v into one 1536x512 buffer)
    transpose_cast_kernel<<<dim3(16, 16), tb, 0, stream>>>(Wq + l * S1, wqkv, 512, 512);
    transpose_cast_kernel<<<dim3(16, 16), tb, 0, stream>>>(Wk + l * S1, wqkv + S1, 512, 512);
    transpose_cast_kernel<<<dim3(16, 16), tb, 0, stream>>>(Wv + l * S1, wqkv + 2 * S1, 512, 512);
    transpose_cast_kernel<<<dim3(16, 16), tb, 0, stream>>>(Wo + l * S1, wo, 512, 512);
    transpose_cast_kernel<<<dim3(64, 16), tb, 0, stream>>>(W1 + l * S2, w1, 512, 2048);
    transpose_cast_kernel<<<dim3(16, 64), tb, 0, stream>>>(W2 + l * S2, w2, 2048, 512);
    bias_concat_kernel<<<6, 256, 0, stream>>>(bq + l * 512, bk + l * 512, bv + l * 512, bqkv);
    // merged QKV projection (bf16 A -> bf16 out, N=1536)
    gemm_bf16<true><<<dim3(12, MBc), 256, 0, stream>>>(xb, wqkv, bqkv, qkvb, N_NODES, 512, 1536, 0);
    // fused edge attention (score + online softmax + aggregation)
    edge_attn_kernel<<<(N_NODES + 3) / 4, 256, 0, stream>>>(qkvb, qkvb + 512, qkvb + 1024,
                                                            rel_embed, offs, esrc, erel, ob, N_NODES, 1536);
    // output projection -> fp32 proj (aliases dead qkvb), then LN1 -> hbb (bf16)
    gemm_bf16<false><<<dim3(4, MBc), 256, 0, stream>>>(ob, wo, bo + l * 512, proj, N_NODES, 512, 512, 0);
    ln_kernel<true, false><<<N_NODES / 4, 256, 0, stream>>>(x_in, proj, g1 + l * 512, bb1 + l * 512, nullptr, hbb, N_NODES);
    // FFN: hbb -> ff1 (bf16, relu); ff1 -> projf (fp32)
    gemm_bf16<true><<<dim3(16, MBc), 256, 0, stream>>>(hbb, w1, b1 + l * 2048, ff1, N_NODES, 512, 2048, 1);
    gemm_bf16<false><<<dim3(4, MBc), 256, 0, stream>>>(ff1, w2, b2 + l * 512, projf, N_NODES, 2048, 512, 0);
    // LN2 -> xout (fp32, harness output / next residual) + xb (bf16, next-layer A)
    ln_kernel<false, true><<<N_NODES / 4, 256, 0, stream>>>(hbb, projf, g2 + l * 512, bb2 + l * 512, xout, xb, N_NODES);
  }
}

// Round 6
// 1432.302 us; speedup vs baseline: 1.9196x; 1.0946x over previous
//
#include <hip/hip_runtime.h>
#include <cstdint>
#include <cstddef>

// ---------------- problem constants ----------------
#define N_NODES 20000
#define N_EDGES 160000
#define HIDDEN  512
#define NHEAD   8
#define HDK     64
#define NLAYER  4
#define FFDIM   2048
#define ATT_SCALE 0.125f   // 1/sqrt(64)

// ---------------- MFMA types ----------------
typedef float  f4  __attribute__((ext_vector_type(4)));
typedef short  s8v __attribute__((ext_vector_type(8)));
typedef __bf16 b8v __attribute__((ext_vector_type(8)));

template <typename V>
__device__ inline auto mfma_try(V a, V b, f4 c, int)
    -> decltype(__builtin_amdgcn_mfma_f32_16x16x32_bf16(a, b, c, 0, 0, 0)) {
  return __builtin_amdgcn_mfma_f32_16x16x32_bf16(a, b, c, 0, 0, 0);
}
template <typename V>
__device__ inline f4 mfma_try(V a, V b, f4 c, long) {
  return __builtin_amdgcn_mfma_f32_16x16x32_bf16(
      __builtin_bit_cast(b8v, a), __builtin_bit_cast(b8v, b), c, 0, 0, 0);
}
__device__ inline f4 mfma_bf16(s8v a, s8v b, f4 c) { return mfma_try(a, b, c, 0); }

__device__ __forceinline__ unsigned short f2bf(float f) {
  unsigned u = __builtin_bit_cast(unsigned, f);
  u += 0x7FFFu + ((u >> 16) & 1u);   // RNE
  return (unsigned short)(u >> 16);
}
__device__ __forceinline__ float bf2f(unsigned short u) {
  return __builtin_bit_cast(float, (unsigned)u << 16);
}

// async global->LDS, 16B per lane; LDS dest is wave-uniform base + lane*16
#define GLOAD_LDS16(gp, lp)                                                   \
  __builtin_amdgcn_global_load_lds(                                           \
      (const __attribute__((address_space(1))) void*)(gp),                    \
      (__attribute__((address_space(3))) void*)(lp), 16, 0, 0)

// ---------------- weight transpose + bf16 cast: in (K x N) fp32 -> out (N x K) bf16 ----------------
__global__ void transpose_cast_kernel(const float* __restrict__ in,
                                      unsigned short* __restrict__ out,
                                      int K, int N) {
  __shared__ float t[32][33];
  int tx = threadIdx.x, ty = threadIdx.y;
  int n0 = blockIdx.x * 32, k0 = blockIdx.y * 32;
#pragma unroll
  for (int i = 0; i < 32; i += 8)
    t[ty + i][tx] = in[(size_t)(k0 + ty + i) * N + n0 + tx];
  __syncthreads();
#pragma unroll
  for (int i = 0; i < 32; i += 8)
    out[(size_t)(n0 + ty + i) * K + k0 + tx] = f2bf(t[tx][ty + i]);
}

// ---------------- fp32 -> bf16 cast ----------------
__global__ void cast_kernel(const float* __restrict__ in, unsigned short* __restrict__ out, int n) {
  int i = blockIdx.x * blockDim.x + threadIdx.x;
  if (i < n) out[i] = f2bf(in[i]);
}

// ---------------- bias concat: [bq | bk | bv] -> 1536 ----------------
__global__ void bias_concat_kernel(const float* __restrict__ a, const float* __restrict__ b,
                                   const float* __restrict__ c, float* __restrict__ out) {
  int i = threadIdx.x + blockIdx.x * blockDim.x;
  if (i < 512) out[i] = a[i];
  else if (i < 1024) out[i] = b[i - 512];
  else if (i < 1536) out[i] = c[i - 1024];
}

// ---------------- GEMM: C[M,N] = A[M,K] @ Bt[N,K]^T + bias, optional relu ----------------
// BK=64: LDS row = 64 elems (8 chunks of 8); chunk q of row r stored at pos q^(r&7).
#define BM 128
#define BN 128
#define BK 64

template <bool OBF16>
__global__ __launch_bounds__(256) void gemm_bf16(
    const unsigned short* __restrict__ A, const unsigned short* __restrict__ Bt,
    const float* __restrict__ bias, void* __restrict__ Cp,
    int M, int K, int N, int relu) {
  __shared__ __align__(16) unsigned short smem[16384];   // As [0,8192) Bs [8192,16384)
  unsigned short* As = smem;
  unsigned short* Bs = smem + 8192;
  int tid = threadIdx.x;
  int wave = tid >> 6, lane = tid & 63;
  int quad = lane >> 4, l16 = lane & 15;
  int wm = (wave >> 1) * 64, wn = (wave & 1) * 64;
  int m0 = blockIdx.y * BM, n0 = blockIdx.x * BN;

  f4 acc[4][4];
#pragma unroll
  for (int i = 0; i < 4; ++i)
#pragma unroll
    for (int j = 0; j < 4; ++j) acc[i][j] = (f4){0.f, 0.f, 0.f, 0.f};

  // staging: round j covers rows [j*32, j*32+32); thread -> row wave*8 + (lane>>3),
  // swizzled global chunk q8; LDS dest (wave-uniform base + lane*16) matches linear id.
  int rbase = wave * 8 + (lane >> 3);
  int q8 = (lane & 7) ^ ((lane >> 3) & 7);
  const unsigned short* aptr[4];
  const unsigned short* bptr[4];
#pragma unroll
  for (int j = 0; j < 4; ++j) {
    int r = j * 32 + rbase;
    int gm = m0 + r; if (gm >= M) gm = M - 1;   // clamp: dup rows never stored
    aptr[j] = A + (size_t)gm * K + q8 * 8;
    bptr[j] = Bt + (size_t)(n0 + r) * K + q8 * 8;
  }

  int nk = K >> 6;
  for (int ks = 0; ks < nk; ++ks) {
#pragma unroll
    for (int j = 0; j < 4; ++j)
      GLOAD_LDS16(aptr[j], &As[j * 2048 + wave * 512]);
#pragma unroll
    for (int j = 0; j < 4; ++j)
      GLOAD_LDS16(bptr[j], &Bs[j * 2048 + wave * 512]);
#pragma unroll
    for (int j = 0; j < 4; ++j) { aptr[j] += BK; bptr[j] += BK; }
    __syncthreads();
#pragma unroll
    for (int s = 0; s < 2; ++s) {
      s8v af[4], bfr[4];
#pragma unroll
      for (int i = 0; i < 4; ++i) {
        int ra = wm + i * 16 + l16;
        int rb = wn + i * 16 + l16;
        af[i]  = *(const s8v*)(&As[ra * 64 + ((((s << 2) | quad) ^ (ra & 7)) * 8)]);
        bfr[i] = *(const s8v*)(&Bs[rb * 64 + ((((s << 2) | quad) ^ (rb & 7)) * 8)]);
      }
#pragma unroll
      for (int mi = 0; mi < 4; ++mi)
#pragma unroll
        for (int ni = 0; ni < 4; ++ni)
          acc[mi][ni] = mfma_bf16(af[mi], bfr[ni], acc[mi][ni]);
    }
    __syncthreads();
  }

  if constexpr (OBF16) {
    // coalesced bf16 epilogue: restage each wave's 16x64 subtile through LDS
    unsigned short* Cs = smem + wave * 1088;   // 16 rows x 64 cols, stride 68
    float bvv[4];
#pragma unroll
    for (int ni = 0; ni < 4; ++ni) bvv[ni] = bias[n0 + wn + ni * 16 + l16];
    int row_l = lane >> 2, cg = lane & 3;
#pragma unroll
    for (int mi = 0; mi < 4; ++mi) {
#pragma unroll
      for (int ni = 0; ni < 4; ++ni) {
#pragma unroll
        for (int r = 0; r < 4; ++r) {
          float val = acc[mi][ni][r] + bvv[ni];
          if (relu) val = fmaxf(val, 0.f);
          Cs[(quad * 4 + r) * 68 + ni * 16 + l16] = f2bf(val);
        }
      }
      s8v v0 = *(const s8v*)(&Cs[row_l * 68 + cg * 16]);
      s8v v1 = *(const s8v*)(&Cs[row_l * 68 + cg * 16 + 8]);
      int grow = m0 + wm + mi * 16 + row_l;
      if (grow < M) {
        unsigned short* cp = (unsigned short*)Cp + (size_t)grow * N + n0 + wn + cg * 16;
        *(s8v*)cp = v0;
        *(s8v*)(cp + 8) = v1;
      }
    }
  } else {
    // fp32 epilogue: 16 lanes x 4B = 64B contiguous per row segment — coalesced
#pragma unroll
    for (int ni = 0; ni < 4; ++ni) {
      int col = n0 + wn + ni * 16 + l16;
      float bv = bias[col];
#pragma unroll
      for (int mi = 0; mi < 4; ++mi) {
#pragma unroll
        for (int r = 0; r < 4; ++r) {
          int row = m0 + wm + mi * 16 + quad * 4 + r;
          if (row < M) {
            float val = acc[mi][ni][r] + bv;
            if (relu) val = fmaxf(val, 0.f);
            ((float*)Cp)[(size_t)row * N + col] = val;
          }
        }
      }
    }
  }
}

// ---------------- CSR build ----------------
__global__ void hist_kernel(const int* __restrict__ dst, int* __restrict__ cnt, int E) {
  int e = blockIdx.x * blockDim.x + threadIdx.x;
  if (e < E) atomicAdd(&cnt[dst[e]], 1);
}

__global__ void scan_kernel(const int* __restrict__ cnt, int* __restrict__ offs, int n) {
  __shared__ int sh[1024];
  __shared__ int carry_sh;
  int tid = threadIdx.x;
  if (tid == 0) carry_sh = 0;
  __syncthreads();
  for (int base = 0; base < n; base += 1024) {
    int v = (base + tid < n) ? cnt[base + tid] : 0;
    sh[tid] = v;
    __syncthreads();
    for (int s = 1; s < 1024; s <<= 1) {
      int t = (tid >= s) ? sh[tid - s] : 0;
      __syncthreads();
      sh[tid] += t;
      __syncthreads();
    }
    int carry = carry_sh;
    if (base + tid < n) offs[base + tid] = carry + sh[tid] - v;
    __syncthreads();
    if (tid == 1023) carry_sh = carry + sh[1023];
    __syncthreads();
  }
  if (tid == 0) offs[n] = carry_sh;
}

__global__ void scatter_kernel(const int* __restrict__ dst, const int* __restrict__ src,
                               const int* __restrict__ relations, const int* __restrict__ offs,
                               int* __restrict__ cursor, int* __restrict__ esrc,
                               int* __restrict__ erel, int E) {
  int e = blockIdx.x * blockDim.x + threadIdx.x;
  if (e < E) {
    int d = dst[e];
    int pos = offs[d] + atomicAdd(&cursor[d], 1);
    esrc[pos] = src[e];
    erel[pos] = relations[e];
  }
}

// ---------------- fused edge attention: one wave per dst node, online softmax ----------------
__global__ void edge_attn_kernel(const unsigned short* __restrict__ q,
                                 const unsigned short* __restrict__ k,
                                 const unsigned short* __restrict__ v,
                                 const float* __restrict__ rel,
                                 const int* __restrict__ offs,
                                 const int* __restrict__ esrc,
                                 const int* __restrict__ erel,
                                 unsigned short* __restrict__ o, int Nn, int STR) {
  int wid = (blockIdx.x * blockDim.x + threadIdx.x) >> 6;
  int lane = threadIdx.x & 63;
  if (wid >= Nn) return;
  int base = (lane >> 3) * HDK + (lane & 7) * 8;

  s8v qv = *(const s8v*)(q + (size_t)wid * STR + base);
  float qf[8];
#pragma unroll
  for (int j = 0; j < 8; ++j) qf[j] = bf2f((unsigned short)qv[j]);

  int beg = offs[wid], end = offs[wid + 1];
  float m = -1e30f, z = 0.f;
  float acc[8];
#pragma unroll
  for (int j = 0; j < 8; ++j) acc[j] = 0.f;

  for (int i = beg; i < end; ++i) {
    int s = esrc[i], r = erel[i];
    s8v kv = *(const s8v*)(k + (size_t)s * STR + base);
    const float* rr = rel + (size_t)r * HIDDEN + base;
    float4 r0 = *(const float4*)rr;
    float4 r1 = *(const float4*)(rr + 4);
    float rf[8] = {r0.x, r0.y, r0.z, r0.w, r1.x, r1.y, r1.z, r1.w};
    float p = 0.f;
#pragma unroll
    for (int j = 0; j < 8; ++j) p += (bf2f((unsigned short)kv[j]) + rf[j]) * qf[j];
    p += __shfl_xor(p, 1, 64);
    p += __shfl_xor(p, 2, 64);
    p += __shfl_xor(p, 4, 64);
    p *= ATT_SCALE;
    float mn = fmaxf(m, p);
    float a = __expf(m - mn);
    float w = __expf(p - mn);
    s8v vv = *(const s8v*)(v + (size_t)s * STR + base);
    z = z * a + w;
#pragma unroll
    for (int j = 0; j < 8; ++j)
      acc[j] = acc[j] * a + w * (bf2f((unsigned short)vv[j]) + rf[j]);
    m = mn;
  }
  float rz = 1.f / (z + 1e-9f);
  s8v ov;
#pragma unroll
  for (int j = 0; j < 8; ++j) ov[j] = (short)f2bf(acc[j] * rz);
  *(s8v*)(o + (size_t)wid * HIDDEN + base) = ov;
}

// ---------------- fused residual add + LayerNorm (one wave per row) ----------------
template <bool XF32, bool WF32>
__global__ void ln_kernel(const void* __restrict__ xp, const float* __restrict__ y,
                          const float* __restrict__ g, const float* __restrict__ b,
                          float* __restrict__ outf, unsigned short* __restrict__ outb, int Nn) {
  int wid = (blockIdx.x * blockDim.x + threadIdx.x) >> 6;
  int lane = threadIdx.x & 63;
  if (wid >= Nn) return;
  const float* yr = y + (size_t)wid * HIDDEN;
  float vals[8];
  float sum = 0.f;
#pragma unroll
  for (int j = 0; j < 8; ++j) {
    int idx = j * 64 + lane;
    float xv;
    if constexpr (XF32) xv = ((const float*)xp)[(size_t)wid * HIDDEN + idx];
    else                xv = bf2f(((const unsigned short*)xp)[(size_t)wid * HIDDEN + idx]);
    vals[j] = xv + yr[idx];
    sum += vals[j];
  }
#pragma unroll
  for (int off = 32; off; off >>= 1) sum += __shfl_xor(sum, off, 64);
  float mean = sum * (1.f / 512.f);
  float sq = 0.f;
#pragma unroll
  for (int j = 0; j < 8; ++j) { float d = vals[j] - mean; sq += d * d; }
#pragma unroll
  for (int off = 32; off; off >>= 1) sq += __shfl_xor(sq, off, 64);
  float rstd = rsqrtf(sq * (1.f / 512.f) + 1e-5f);
#pragma unroll
  for (int j = 0; j < 8; ++j) {
    int idx = j * 64 + lane;
    float val = (vals[j] - mean) * rstd * g[idx] + b[idx];
    if constexpr (WF32) outf[(size_t)wid * HIDDEN + idx] = val;
    outb[(size_t)wid * HIDDEN + idx] = f2bf(val);
  }
}

// ---------------- host orchestration ----------------
extern "C" void kernel_launch(void* const* d_in, const int* in_sizes, int n_in,
                              void* d_out, int out_size, void* d_ws, size_t ws_size,
                              hipStream_t stream) {
  const float* x0        = (const float*)d_in[0];
  const int*   relations = (const int*)d_in[1];
  const int*   src       = (const int*)d_in[2];
  const int*   dst       = (const int*)d_in[3];
  const float* rel_embed = (const float*)d_in[4];
  const float* Wq = (const float*)d_in[5];  const float* bq = (const float*)d_in[6];
  const float* Wk = (const float*)d_in[7];  const float* bk = (const float*)d_in[8];
  const float* Wv = (const float*)d_in[9];  const float* bv = (const float*)d_in[10];
  const float* Wo = (const float*)d_in[11]; const float* bo = (const float*)d_in[12];
  const float* W1 = (const float*)d_in[13]; const float* b1 = (const float*)d_in[14];
  const float* W2 = (const float*)d_in[15]; const float* b2 = (const float*)d_in[16];
  const float* g1  = (const float*)d_in[17]; const float* bb1 = (const float*)d_in[18];
  const float* g2  = (const float*)d_in[19]; const float* bb2 = (const float*)d_in[20];
  float* xout = (float*)d_out;

  const size_t S1 = 512 * 512;
  const size_t S2 = 512 * 2048;
  const size_t NH = (size_t)N_NODES * HIDDEN;   // 10,240,000

  // ---- workspace layout (~172 MiB) ----
  unsigned short* wqkv = (unsigned short*)d_ws; // 3*S1 (rows 0-511 q, 512-1023 k, 1024-1535 v)
  unsigned short* wo = wqkv + 3 * S1;
  unsigned short* w1 = wo + S1;                 // S2
  unsigned short* w2 = w1 + S2;                 // S2
  float* bqkv = (float*)(w2 + S2);              // 1536 fp32 concat bias
  unsigned short* arena = (unsigned short*)(bqkv + 1536);  // 4*NH bf16
  unsigned short* qkvb = arena;                 // 3*NH, row stride 1536
  unsigned short* ob   = arena + 3 * NH;        // NH, row stride 512
  unsigned short* ff1  = arena;                 // 4*NH (qkv+ob dead by FF1 time)
  float* proj = (float*)arena;                  // NH fp32, aliases qkvb (dead at Wo time)
  unsigned short* hbb = arena + 4 * NH;         // NH bf16 (LN1 out)
  unsigned short* xb  = hbb + NH;               // NH bf16 (layer input)
  float* projf = (float*)(xb + NH);             // NH fp32 (FF2 out)
  int* cnt    = (int*)(projf + NH);
  int* offs   = cnt + N_NODES;
  int* cursor = offs + N_NODES + 1;
  int* esrc   = cursor + N_NODES;
  int* erel   = esrc + N_EDGES;

  // ---- CSR build (once per call) ----
  hipMemsetAsync(cnt, 0, N_NODES * sizeof(int), stream);
  hipMemsetAsync(cursor, 0, N_NODES * sizeof(int), stream);
  hist_kernel<<<(N_EDGES + 255) / 256, 256, 0, stream>>>(dst, cnt, N_EDGES);
  scan_kernel<<<1, 1024, 0, stream>>>(cnt, offs, N_NODES);
  scatter_kernel<<<(N_EDGES + 255) / 256, 256, 0, stream>>>(dst, src, relations, offs, cursor, esrc, erel, N_EDGES);

  // ---- layer-0 input cast ----
  cast_kernel<<<(int)((NH + 255) / 256), 256, 0, stream>>>(x0, xb, (int)NH);

  const int MBc = (N_NODES + BM - 1) / BM;   // 157
  dim3 tb(32, 8);

  for (int l = 0; l < NLAYER; ++l) {
    const float* x_in = (l == 0) ? x0 : xout;
    // weight transpose/cast for this layer (q/k/v into one 1536x512 buffer)
    transpose_cast_kernel<<<dim3(16, 16), tb, 0, stream>>>(Wq + l * S1, wqkv, 512, 512);
    transpose_cast_kernel<<<dim3(16, 16), tb, 0, stream>>>(Wk + l * S1, wqkv + S1, 512, 512);
    transpose_cast_kernel<<<dim3(16, 16), tb, 0, stream>>>(Wv + l * S1, wqkv + 2 * S1, 512, 512);
    transpose_cast_kernel<<<dim3(16, 16), tb, 0, stream>>>(Wo + l * S1, wo, 512, 512);
    transpose_cast_kernel<<<dim3(64, 16), tb, 0, stream>>>(W1 + l * S2, w1, 512, 2048);
    transpose_cast_kernel<<<dim3(16, 64), tb, 0, stream>>>(W2 + l * S2, w2, 2048, 512);
    bias_concat_kernel<<<6, 256, 0, stream>>>(bq + l * 512, bk + l * 512, bv + l * 512, bqkv);
    // merged QKV projection (bf16 A -> bf16 out, N=1536)
    gemm_bf16<true><<<dim3(12, MBc), 256, 0, stream>>>(xb, wqkv, bqkv, qkvb, N_NODES, 512, 1536, 0);
    // fused edge attention (score + online softmax + aggregation)
    edge_attn_kernel<<<(N_NODES + 3) / 4, 256, 0, stream>>>(qkvb, qkvb + 512, qkvb + 1024,
                                                            rel_embed, offs, esrc, erel, ob, N_NODES, 1536);
    // output projection -> fp32 proj (aliases dead qkvb), then LN1 -> hbb (bf16)
    gemm_bf16<false><<<dim3(4, MBc), 256, 0, stream>>>(ob, wo, bo + l * 512, proj, N_NODES, 512, 512, 0);
    ln_kernel<true, false><<<N_NODES / 4, 256, 0, stream>>>(x_in, proj, g1 + l * 512, bb1 + l * 512, nullptr, hbb, N_NODES);
    // FFN: hbb -> ff1 (bf16, relu); ff1 -> projf (fp32)
    gemm_bf16<true><<<dim3(16, MBc), 256, 0, stream>>>(hbb, w1, b1 + l * 2048, ff1, N_NODES, 512, 2048, 1);
    gemm_bf16<false><<<dim3(4, MBc), 256, 0, stream>>>(ff1, w2, b2 + l * 512, projf, N_NODES, 2048, 512, 0);
    // LN2 -> xout (fp32, harness output / next residual) + xb (bf16, next-layer A)
    ln_kernel<false, true><<<N_NODES / 4, 256, 0, stream>>>(hbb, projf, g2 + l * 512, bb2 + l * 512, xout, xb, N_NODES);
  }
}

// Round 7
// 1414.848 us; speedup vs baseline: 1.9433x; 1.0123x over previous
//
#include <hip/hip_runtime.h>
#include <cstdint>
#include <cstddef>

// ---------------- problem constants ----------------
#define N_NODES 20000
#define N_EDGES 160000
#define HIDDEN  512
#define NHEAD   8
#define HDK     64
#define NLAYER  4
#define FFDIM   2048
#define ATT_SCALE 0.125f   // 1/sqrt(64)

// ---------------- MFMA types ----------------
typedef float  f4  __attribute__((ext_vector_type(4)));
typedef short  s8v __attribute__((ext_vector_type(8)));
typedef __bf16 b8v __attribute__((ext_vector_type(8)));

template <typename V>
__device__ inline auto mfma_try(V a, V b, f4 c, int)
    -> decltype(__builtin_amdgcn_mfma_f32_16x16x32_bf16(a, b, c, 0, 0, 0)) {
  return __builtin_amdgcn_mfma_f32_16x16x32_bf16(a, b, c, 0, 0, 0);
}
template <typename V>
__device__ inline f4 mfma_try(V a, V b, f4 c, long) {
  return __builtin_amdgcn_mfma_f32_16x16x32_bf16(
      __builtin_bit_cast(b8v, a), __builtin_bit_cast(b8v, b), c, 0, 0, 0);
}
__device__ inline f4 mfma_bf16(s8v a, s8v b, f4 c) { return mfma_try(a, b, c, 0); }

__device__ __forceinline__ unsigned short f2bf(float f) {
  unsigned u = __builtin_bit_cast(unsigned, f);
  u += 0x7FFFu + ((u >> 16) & 1u);   // RNE
  return (unsigned short)(u >> 16);
}
__device__ __forceinline__ float bf2f(unsigned short u) {
  return __builtin_bit_cast(float, (unsigned)u << 16);
}

// async global->LDS, 16B per lane; LDS dest is wave-uniform base + lane*16
#define GLOAD_LDS16(gp, lp)                                                   \
  __builtin_amdgcn_global_load_lds(                                           \
      (const __attribute__((address_space(1))) void*)(gp),                    \
      (__attribute__((address_space(3))) void*)(lp), 16, 0, 0)

// ---------------- weight transpose + bf16 cast: in (K x N) fp32 -> out (N x K) bf16 ----------------
__global__ void transpose_cast_kernel(const float* __restrict__ in,
                                      unsigned short* __restrict__ out,
                                      int K, int N) {
  __shared__ float t[32][33];
  int tx = threadIdx.x, ty = threadIdx.y;
  int n0 = blockIdx.x * 32, k0 = blockIdx.y * 32;
#pragma unroll
  for (int i = 0; i < 32; i += 8)
    t[ty + i][tx] = in[(size_t)(k0 + ty + i) * N + n0 + tx];
  __syncthreads();
#pragma unroll
  for (int i = 0; i < 32; i += 8)
    out[(size_t)(n0 + ty + i) * K + k0 + tx] = f2bf(t[tx][ty + i]);
}

// ---------------- fp32 -> bf16 cast ----------------
__global__ void cast_kernel(const float* __restrict__ in, unsigned short* __restrict__ out, int n) {
  int i = blockIdx.x * blockDim.x + threadIdx.x;
  if (i < n) out[i] = f2bf(in[i]);
}

// ---------------- bias concat: [bq | bk | bv] -> 1536 ----------------
__global__ void bias_concat_kernel(const float* __restrict__ a, const float* __restrict__ b,
                                   const float* __restrict__ c, float* __restrict__ out) {
  int i = threadIdx.x + blockIdx.x * blockDim.x;
  if (i < 512) out[i] = a[i];
  else if (i < 1024) out[i] = b[i - 512];
  else if (i < 1536) out[i] = c[i - 1024];
}

// ---------------- GEMM: C[M,N] = A[M,K] @ Bt[N,K]^T + bias, optional relu ----------------
// BK=64: LDS row = 64 elems (8 chunks of 8); chunk q of row r stored at pos q^(r&7).
// XCD-aware block permutation: HW round-robins launch id i over 8 XCDs; we map
// work id w = (i&7)*(T/8) + (i>>3) so each XCD gets a CONTIGUOUS work range ->
// the n-blocks sharing an A m-stripe run concurrently on ONE XCD's L2.
#define BM 128
#define BN 128
#define BK 64

template <bool OBF16>
__global__ __launch_bounds__(256) void gemm_bf16(
    const unsigned short* __restrict__ A, const unsigned short* __restrict__ Bt,
    const float* __restrict__ bias, void* __restrict__ Cp,
    int M, int K, int N, int relu) {
  __shared__ __align__(16) unsigned short smem[16384];   // As [0,8192) Bs [8192,16384)
  unsigned short* As = smem;
  unsigned short* Bs = smem + 8192;
  int tid = threadIdx.x;
  int wave = tid >> 6, lane = tid & 63;
  int quad = lane >> 4, l16 = lane & 15;
  int wm = (wave >> 1) * 64, wn = (wave & 1) * 64;

  // XCD swizzle
  int T = gridDim.x * gridDim.y;
  int i = blockIdx.y * gridDim.x + blockIdx.x;
  int C = T >> 3;
  int w = (i < (C << 3)) ? ((i & 7) * C + (i >> 3)) : i;
  int bx = w % gridDim.x, by = w / gridDim.x;
  int m0 = by * BM, n0 = bx * BN;

  f4 acc[4][4];
#pragma unroll
  for (int i2 = 0; i2 < 4; ++i2)
#pragma unroll
    for (int j = 0; j < 4; ++j) acc[i2][j] = (f4){0.f, 0.f, 0.f, 0.f};

  // staging: round j covers rows [j*32, j*32+32); thread -> row wave*8 + (lane>>3),
  // swizzled global chunk q8; LDS dest (wave-uniform base + lane*16) matches linear id.
  int rbase = wave * 8 + (lane >> 3);
  int q8 = (lane & 7) ^ ((lane >> 3) & 7);
  const unsigned short* aptr[4];
  const unsigned short* bptr[4];
#pragma unroll
  for (int j = 0; j < 4; ++j) {
    int r = j * 32 + rbase;
    int gm = m0 + r; if (gm >= M) gm = M - 1;   // clamp: dup rows never stored
    aptr[j] = A + (size_t)gm * K + q8 * 8;
    bptr[j] = Bt + (size_t)(n0 + r) * K + q8 * 8;
  }

  int nk = K >> 6;
  for (int ks = 0; ks < nk; ++ks) {
#pragma unroll
    for (int j = 0; j < 4; ++j)
      GLOAD_LDS16(aptr[j], &As[j * 2048 + wave * 512]);
#pragma unroll
    for (int j = 0; j < 4; ++j)
      GLOAD_LDS16(bptr[j], &Bs[j * 2048 + wave * 512]);
#pragma unroll
    for (int j = 0; j < 4; ++j) { aptr[j] += BK; bptr[j] += BK; }
    __syncthreads();
#pragma unroll
    for (int s = 0; s < 2; ++s) {
      s8v af[4], bfr[4];
#pragma unroll
      for (int i2 = 0; i2 < 4; ++i2) {
        int ra = wm + i2 * 16 + l16;
        int rb = wn + i2 * 16 + l16;
        af[i2]  = *(const s8v*)(&As[ra * 64 + ((((s << 2) | quad) ^ (ra & 7)) * 8)]);
        bfr[i2] = *(const s8v*)(&Bs[rb * 64 + ((((s << 2) | quad) ^ (rb & 7)) * 8)]);
      }
#pragma unroll
      for (int mi = 0; mi < 4; ++mi)
#pragma unroll
        for (int ni = 0; ni < 4; ++ni)
          acc[mi][ni] = mfma_bf16(af[mi], bfr[ni], acc[mi][ni]);
    }
    __syncthreads();
  }

  if constexpr (OBF16) {
    // coalesced bf16 epilogue: restage each wave's 16x64 subtile through LDS
    unsigned short* Cs = smem + wave * 1088;   // 16 rows x 64 cols, stride 68
    float bvv[4];
#pragma unroll
    for (int ni = 0; ni < 4; ++ni) bvv[ni] = bias[n0 + wn + ni * 16 + l16];
    int row_l = lane >> 2, cg = lane & 3;
#pragma unroll
    for (int mi = 0; mi < 4; ++mi) {
#pragma unroll
      for (int ni = 0; ni < 4; ++ni) {
#pragma unroll
        for (int r = 0; r < 4; ++r) {
          float val = acc[mi][ni][r] + bvv[ni];
          if (relu) val = fmaxf(val, 0.f);
          Cs[(quad * 4 + r) * 68 + ni * 16 + l16] = f2bf(val);
        }
      }
      s8v v0 = *(const s8v*)(&Cs[row_l * 68 + cg * 16]);
      s8v v1 = *(const s8v*)(&Cs[row_l * 68 + cg * 16 + 8]);
      int grow = m0 + wm + mi * 16 + row_l;
      if (grow < M) {
        unsigned short* cp = (unsigned short*)Cp + (size_t)grow * N + n0 + wn + cg * 16;
        *(s8v*)cp = v0;
        *(s8v*)(cp + 8) = v1;
      }
    }
  } else {
    // fp32 epilogue: 16 lanes x 4B = 64B contiguous per row segment — coalesced
#pragma unroll
    for (int ni = 0; ni < 4; ++ni) {
      int col = n0 + wn + ni * 16 + l16;
      float bv = bias[col];
#pragma unroll
      for (int mi = 0; mi < 4; ++mi) {
#pragma unroll
        for (int r = 0; r < 4; ++r) {
          int row = m0 + wm + mi * 16 + quad * 4 + r;
          if (row < M) {
            float val = acc[mi][ni][r] + bv;
            if (relu) val = fmaxf(val, 0.f);
            ((float*)Cp)[(size_t)row * N + col] = val;
          }
        }
      }
    }
  }
}

// ---------------- CSR build ----------------
__global__ void hist_kernel(const int* __restrict__ dst, int* __restrict__ cnt, int E) {
  int e = blockIdx.x * blockDim.x + threadIdx.x;
  if (e < E) atomicAdd(&cnt[dst[e]], 1);
}

__global__ void scan_kernel(const int* __restrict__ cnt, int* __restrict__ offs, int n) {
  __shared__ int sh[1024];
  __shared__ int carry_sh;
  int tid = threadIdx.x;
  if (tid == 0) carry_sh = 0;
  __syncthreads();
  for (int base = 0; base < n; base += 1024) {
    int v = (base + tid < n) ? cnt[base + tid] : 0;
    sh[tid] = v;
    __syncthreads();
    for (int s = 1; s < 1024; s <<= 1) {
      int t = (tid >= s) ? sh[tid - s] : 0;
      __syncthreads();
      sh[tid] += t;
      __syncthreads();
    }
    int carry = carry_sh;
    if (base + tid < n) offs[base + tid] = carry + sh[tid] - v;
    __syncthreads();
    if (tid == 1023) carry_sh = carry + sh[1023];
    __syncthreads();
  }
  if (tid == 0) offs[n] = carry_sh;
}

__global__ void scatter_kernel(const int* __restrict__ dst, const int* __restrict__ src,
                               const int* __restrict__ relations, const int* __restrict__ offs,
                               int* __restrict__ cursor, int* __restrict__ esrc,
                               int* __restrict__ erel, int E) {
  int e = blockIdx.x * blockDim.x + threadIdx.x;
  if (e < E) {
    int d = dst[e];
    int pos = offs[d] + atomicAdd(&cursor[d], 1);
    esrc[pos] = src[e];
    erel[pos] = relations[e];
  }
}

// ---------------- fused edge attention: one wave per dst node, online softmax ----------------
__global__ void edge_attn_kernel(const unsigned short* __restrict__ q,
                                 const unsigned short* __restrict__ k,
                                 const unsigned short* __restrict__ v,
                                 const float* __restrict__ rel,
                                 const int* __restrict__ offs,
                                 const int* __restrict__ esrc,
                                 const int* __restrict__ erel,
                                 unsigned short* __restrict__ o, int Nn, int STR) {
  int wid = (blockIdx.x * blockDim.x + threadIdx.x) >> 6;
  int lane = threadIdx.x & 63;
  if (wid >= Nn) return;
  int base = (lane >> 3) * HDK + (lane & 7) * 8;

  s8v qv = *(const s8v*)(q + (size_t)wid * STR + base);
  float qf[8];
#pragma unroll
  for (int j = 0; j < 8; ++j) qf[j] = bf2f((unsigned short)qv[j]);

  int beg = offs[wid], end = offs[wid + 1];
  float m = -1e30f, z = 0.f;
  float acc[8];
#pragma unroll
  for (int j = 0; j < 8; ++j) acc[j] = 0.f;

  for (int i = beg; i < end; ++i) {
    int s = esrc[i], r = erel[i];
    s8v kv = *(const s8v*)(k + (size_t)s * STR + base);
    const float* rr = rel + (size_t)r * HIDDEN + base;
    float4 r0 = *(const float4*)rr;
    float4 r1 = *(const float4*)(rr + 4);
    float rf[8] = {r0.x, r0.y, r0.z, r0.w, r1.x, r1.y, r1.z, r1.w};
    float p = 0.f;
#pragma unroll
    for (int j = 0; j < 8; ++j) p += (bf2f((unsigned short)kv[j]) + rf[j]) * qf[j];
    p += __shfl_xor(p, 1, 64);
    p += __shfl_xor(p, 2, 64);
    p += __shfl_xor(p, 4, 64);
    p *= ATT_SCALE;
    float mn = fmaxf(m, p);
    float a = __expf(m - mn);
    float w = __expf(p - mn);
    s8v vv = *(const s8v*)(v + (size_t)s * STR + base);
    z = z * a + w;
#pragma unroll
    for (int j = 0; j < 8; ++j)
      acc[j] = acc[j] * a + w * (bf2f((unsigned short)vv[j]) + rf[j]);
    m = mn;
  }
  float rz = 1.f / (z + 1e-9f);
  s8v ov;
#pragma unroll
  for (int j = 0; j < 8; ++j) ov[j] = (short)f2bf(acc[j] * rz);
  *(s8v*)(o + (size_t)wid * HIDDEN + base) = ov;
}

// ---------------- fused residual add + LayerNorm (one wave per row) ----------------
template <bool XF32, bool WF32>
__global__ void ln_kernel(const void* __restrict__ xp, const float* __restrict__ y,
                          const float* __restrict__ g, const float* __restrict__ b,
                          float* __restrict__ outf, unsigned short* __restrict__ outb, int Nn) {
  int wid = (blockIdx.x * blockDim.x + threadIdx.x) >> 6;
  int lane = threadIdx.x & 63;
  if (wid >= Nn) return;
  const float* yr = y + (size_t)wid * HIDDEN;
  float vals[8];
  float sum = 0.f;
#pragma unroll
  for (int j = 0; j < 8; ++j) {
    int idx = j * 64 + lane;
    float xv;
    if constexpr (XF32) xv = ((const float*)xp)[(size_t)wid * HIDDEN + idx];
    else                xv = bf2f(((const unsigned short*)xp)[(size_t)wid * HIDDEN + idx]);
    vals[j] = xv + yr[idx];
    sum += vals[j];
  }
#pragma unroll
  for (int off = 32; off; off >>= 1) sum += __shfl_xor(sum, off, 64);
  float mean = sum * (1.f / 512.f);
  float sq = 0.f;
#pragma unroll
  for (int j = 0; j < 8; ++j) { float d = vals[j] - mean; sq += d * d; }
#pragma unroll
  for (int off = 32; off; off >>= 1) sq += __shfl_xor(sq, off, 64);
  float rstd = rsqrtf(sq * (1.f / 512.f) + 1e-5f);
#pragma unroll
  for (int j = 0; j < 8; ++j) {
    int idx = j * 64 + lane;
    float val = (vals[j] - mean) * rstd * g[idx] + b[idx];
    if constexpr (WF32) outf[(size_t)wid * HIDDEN + idx] = val;
    outb[(size_t)wid * HIDDEN + idx] = f2bf(val);
  }
}

// ---------------- host orchestration ----------------
extern "C" void kernel_launch(void* const* d_in, const int* in_sizes, int n_in,
                              void* d_out, int out_size, void* d_ws, size_t ws_size,
                              hipStream_t stream) {
  const float* x0        = (const float*)d_in[0];
  const int*   relations = (const int*)d_in[1];
  const int*   src       = (const int*)d_in[2];
  const int*   dst       = (const int*)d_in[3];
  const float* rel_embed = (const float*)d_in[4];
  const float* Wq = (const float*)d_in[5];  const float* bq = (const float*)d_in[6];
  const float* Wk = (const float*)d_in[7];  const float* bk = (const float*)d_in[8];
  const float* Wv = (const float*)d_in[9];  const float* bv = (const float*)d_in[10];
  const float* Wo = (const float*)d_in[11]; const float* bo = (const float*)d_in[12];
  const float* W1 = (const float*)d_in[13]; const float* b1 = (const float*)d_in[14];
  const float* W2 = (const float*)d_in[15]; const float* b2 = (const float*)d_in[16];
  const float* g1  = (const float*)d_in[17]; const float* bb1 = (const float*)d_in[18];
  const float* g2  = (const float*)d_in[19]; const float* bb2 = (const float*)d_in[20];
  float* xout = (float*)d_out;

  const size_t S1 = 512 * 512;
  const size_t S2 = 512 * 2048;
  const size_t NH = (size_t)N_NODES * HIDDEN;   // 10,240,000

  // ---- workspace layout (~172 MiB) ----
  unsigned short* wqkv = (unsigned short*)d_ws; // 3*S1 (rows 0-511 q, 512-1023 k, 1024-1535 v)
  unsigned short* wo = wqkv + 3 * S1;
  unsigned short* w1 = wo + S1;                 // S2
  unsigned short* w2 = w1 + S2;                 // S2
  float* bqkv = (float*)(w2 + S2);              // 1536 fp32 concat bias
  unsigned short* arena = (unsigned short*)(bqkv + 1536);  // 4*NH bf16
  unsigned short* qkvb = arena;                 // 3*NH, row stride 1536
  unsigned short* ob   = arena + 3 * NH;        // NH, row stride 512
  unsigned short* ff1  = arena;                 // 4*NH (qkv+ob dead by FF1 time)
  float* proj = (float*)arena;                  // NH fp32, aliases qkvb (dead at Wo time)
  unsigned short* hbb = arena + 4 * NH;         // NH bf16 (LN1 out)
  unsigned short* xb  = hbb + NH;               // NH bf16 (layer input)
  float* projf = (float*)(xb + NH);             // NH fp32 (FF2 out)
  int* cnt    = (int*)(projf + NH);
  int* offs   = cnt + N_NODES;
  int* cursor = offs + N_NODES + 1;
  int* esrc   = cursor + N_NODES;
  int* erel   = esrc + N_EDGES;

  // ---- CSR build (once per call) ----
  hipMemsetAsync(cnt, 0, N_NODES * sizeof(int), stream);
  hipMemsetAsync(cursor, 0, N_NODES * sizeof(int), stream);
  hist_kernel<<<(N_EDGES + 255) / 256, 256, 0, stream>>>(dst, cnt, N_EDGES);
  scan_kernel<<<1, 1024, 0, stream>>>(cnt, offs, N_NODES);
  scatter_kernel<<<(N_EDGES + 255) / 256, 256, 0, stream>>>(dst, src, relations, offs, cursor, esrc, erel, N_EDGES);

  // ---- layer-0 input cast ----
  cast_kernel<<<(int)((NH + 255) / 256), 256, 0, stream>>>(x0, xb, (int)NH);

  const int MBc = (N_NODES + BM - 1) / BM;   // 157
  dim3 tb(32, 8);

  for (int l = 0; l < NLAYER; ++l) {
    const float* x_in = (l == 0) ? x0 : xout;
    // weight transpose/cast for this layer (q/k/v into one 1536x512 buffer)
    transpose_cast_kernel<<<dim3(16, 16), tb, 0, stream>>>(Wq + l * S1, wqkv, 512, 512);
    transpose_cast_kernel<<<dim3(16, 16), tb, 0, stream>>>(Wk + l * S1, wqkv + S1, 512, 512);
    transpose_cast_kernel<<<dim3(16, 16), tb, 0, stream>>>(Wv + l * S1, wqkv + 2 * S1, 512, 512);
    transpose_cast_kernel<<<dim3(16, 16), tb, 0, stream>>>(Wo + l * S1, wo, 512, 512);
    transpose_cast_kernel<<<dim3(64, 16), tb, 0, stream>>>(W1 + l * S2, w1, 512, 2048);
    transpose_cast_kernel<<<dim3(16, 64), tb, 0, stream>>>(W2 + l * S2, w2, 2048, 512);
    bias_concat_kernel<<<6, 256, 0, stream>>>(bq + l * 512, bk + l * 512, bv + l * 512, bqkv);
    // merged QKV projection (bf16 A -> bf16 out, N=1536)
    gemm_bf16<true><<<dim3(12, MBc), 256, 0, stream>>>(xb, wqkv, bqkv, qkvb, N_NODES, 512, 1536, 0);
    // fused edge attention (score + online softmax + aggregation)
    edge_attn_kernel<<<(N_NODES + 3) / 4, 256, 0, stream>>>(qkvb, qkvb + 512, qkvb + 1024,
                                                            rel_embed, offs, esrc, erel, ob, N_NODES, 1536);
    // output projection -> fp32 proj (aliases dead qkvb), then LN1 -> hbb (bf16)
    gemm_bf16<false><<<dim3(4, MBc), 256, 0, stream>>>(ob, wo, bo + l * 512, proj, N_NODES, 512, 512, 0);
    ln_kernel<true, false><<<N_NODES / 4, 256, 0, stream>>>(x_in, proj, g1 + l * 512, bb1 + l * 512, nullptr, hbb, N_NODES);
    // FFN: hbb -> ff1 (bf16, relu); ff1 -> projf (fp32)
    gemm_bf16<true><<<dim3(16, MBc), 256, 0, stream>>>(hbb, w1, b1 + l * 2048, ff1, N_NODES, 512, 2048, 1);
    gemm_bf16<false><<<dim3(4, MBc), 256, 0, stream>>>(ff1, w2, b2 + l * 512, projf, N_NODES, 2048, 512, 0);
    // LN2 -> xout (fp32, harness output / next residual) + xb (bf16, next-layer A)
    ln_kernel<false, true><<<N_NODES / 4, 256, 0, stream>>>(hbb, projf, g2 + l * 512, bb2 + l * 512, xout, xb, N_NODES);
  }
}

// Round 8
// 1238.133 us; speedup vs baseline: 2.2207x; 1.1427x over previous
//
#include <hip/hip_runtime.h>
#include <cstdint>
#include <cstddef>

// ---------------- problem constants ----------------
#define N_NODES 20000
#define N_EDGES 160000
#define HIDDEN  512
#define NHEAD   8
#define HDK     64
#define NLAYER  4
#define FFDIM   2048
#define ATT_SCALE 0.125f   // 1/sqrt(64)
#define S1C 262144         // 512*512
#define S2C 1048576        // 512*2048

// ---------------- MFMA types ----------------
typedef float  f4  __attribute__((ext_vector_type(4)));
typedef short  s8v __attribute__((ext_vector_type(8)));
typedef __bf16 b8v __attribute__((ext_vector_type(8)));

template <typename V>
__device__ inline auto mfma_try(V a, V b, f4 c, int)
    -> decltype(__builtin_amdgcn_mfma_f32_16x16x32_bf16(a, b, c, 0, 0, 0)) {
  return __builtin_amdgcn_mfma_f32_16x16x32_bf16(a, b, c, 0, 0, 0);
}
template <typename V>
__device__ inline f4 mfma_try(V a, V b, f4 c, long) {
  return __builtin_amdgcn_mfma_f32_16x16x32_bf16(
      __builtin_bit_cast(b8v, a), __builtin_bit_cast(b8v, b), c, 0, 0, 0);
}
__device__ inline f4 mfma_bf16(s8v a, s8v b, f4 c) { return mfma_try(a, b, c, 0); }

__device__ __forceinline__ unsigned short f2bf(float f) {
  unsigned u = __builtin_bit_cast(unsigned, f);
  u += 0x7FFFu + ((u >> 16) & 1u);   // RNE
  return (unsigned short)(u >> 16);
}
__device__ __forceinline__ float bf2f(unsigned short u) {
  return __builtin_bit_cast(float, (unsigned)u << 16);
}

// async global->LDS, 16B per lane; LDS dest is wave-uniform base + lane*16
#define GLOAD_LDS16(gp, lp)                                                   \
  __builtin_amdgcn_global_load_lds(                                           \
      (const __attribute__((address_space(1))) void*)(gp),                    \
      (__attribute__((address_space(3))) void*)(lp), 16, 0, 0)

// ---------------- fp32 -> bf16 cast ----------------
__global__ void cast_kernel(const float* __restrict__ in, unsigned short* __restrict__ out, int n) {
  int i = blockIdx.x * blockDim.x + threadIdx.x;
  if (i < n) out[i] = f2bf(in[i]);
}

// ---------------- batched per-layer weight prep: 6 transposes + bias concat, ONE dispatch ----
// blocks [0,1024): Wq/Wk/Wv/Wo 512x512 (256 tiles each); [1024,2048): W1 512x2048;
// [2048,3072): W2 2048x512; [3072,3078): bias concat.
__global__ void weight_prep_kernel(const float* __restrict__ Wq, const float* __restrict__ Wk,
                                   const float* __restrict__ Wv, const float* __restrict__ Wo_,
                                   const float* __restrict__ W1, const float* __restrict__ W2,
                                   const float* __restrict__ bq, const float* __restrict__ bk,
                                   const float* __restrict__ bv,
                                   unsigned short* __restrict__ wqkv, unsigned short* __restrict__ wo,
                                   unsigned short* __restrict__ w1, unsigned short* __restrict__ w2,
                                   float* __restrict__ bqkv) {
  int id = blockIdx.x;
  if (id >= 3072) {   // bias concat
    int i = (id - 3072) * 256 + threadIdx.y * 32 + threadIdx.x;
    if (i < 512) bqkv[i] = bq[i];
    else if (i < 1024) bqkv[i] = bk[i - 512];
    else if (i < 1536) bqkv[i] = bv[i - 1024];
    return;
  }
  const float* in; unsigned short* out; int K, N, bx, by;
  if (id < 1024) {
    int m = id >> 8, t = id & 255;
    in = (m == 0) ? Wq : (m == 1) ? Wk : (m == 2) ? Wv : Wo_;
    out = (m == 3) ? wo : wqkv + m * S1C;
    K = 512; N = 512; bx = t & 15; by = t >> 4;
  } else if (id < 2048) {
    int t = id - 1024;
    in = W1; out = w1; K = 512; N = 2048; bx = t & 63; by = t >> 6;
  } else {
    int t = id - 2048;
    in = W2; out = w2; K = 2048; N = 512; bx = t & 15; by = t >> 4;
  }
  __shared__ float t32[32][33];
  int tx = threadIdx.x, ty = threadIdx.y;
  int n0 = bx * 32, k0 = by * 32;
#pragma unroll
  for (int i = 0; i < 32; i += 8)
    t32[ty + i][tx] = in[(size_t)(k0 + ty + i) * N + n0 + tx];
  __syncthreads();
#pragma unroll
  for (int i = 0; i < 32; i += 8)
    out[(size_t)(n0 + ty + i) * K + k0 + tx] = f2bf(t32[tx][ty + i]);
}

// ---------------- GEMM: C[M,N] = A[M,K] @ Bt[N,K]^T + bias, optional relu ----------------
// BK=64, XOR-swizzled LDS (chunk q of row r at pos q^(r&7)), XCD-aware block permutation.
#define BM 128
#define BN 128
#define BK 64

template <bool OBF16>
__global__ __launch_bounds__(256) void gemm_bf16(
    const unsigned short* __restrict__ A, const unsigned short* __restrict__ Bt,
    const float* __restrict__ bias, void* __restrict__ Cp,
    int M, int K, int N, int relu) {
  __shared__ __align__(16) unsigned short smem[16384];   // As [0,8192) Bs [8192,16384)
  unsigned short* As = smem;
  unsigned short* Bs = smem + 8192;
  int tid = threadIdx.x;
  int wave = tid >> 6, lane = tid & 63;
  int quad = lane >> 4, l16 = lane & 15;
  int wm = (wave >> 1) * 64, wn = (wave & 1) * 64;

  // XCD swizzle: contiguous work range per XCD
  int T = gridDim.x * gridDim.y;
  int i = blockIdx.y * gridDim.x + blockIdx.x;
  int C = T >> 3;
  int w = (i < (C << 3)) ? ((i & 7) * C + (i >> 3)) : i;
  int bx = w % gridDim.x, by = w / gridDim.x;
  int m0 = by * BM, n0 = bx * BN;

  f4 acc[4][4];
#pragma unroll
  for (int i2 = 0; i2 < 4; ++i2)
#pragma unroll
    for (int j = 0; j < 4; ++j) acc[i2][j] = (f4){0.f, 0.f, 0.f, 0.f};

  int rbase = wave * 8 + (lane >> 3);
  int q8 = (lane & 7) ^ ((lane >> 3) & 7);
  const unsigned short* aptr[4];
  const unsigned short* bptr[4];
#pragma unroll
  for (int j = 0; j < 4; ++j) {
    int r = j * 32 + rbase;
    int gm = m0 + r; if (gm >= M) gm = M - 1;   // clamp: dup rows never stored
    aptr[j] = A + (size_t)gm * K + q8 * 8;
    bptr[j] = Bt + (size_t)(n0 + r) * K + q8 * 8;
  }

  int nk = K >> 6;
  for (int ks = 0; ks < nk; ++ks) {
#pragma unroll
    for (int j = 0; j < 4; ++j)
      GLOAD_LDS16(aptr[j], &As[j * 2048 + wave * 512]);
#pragma unroll
    for (int j = 0; j < 4; ++j)
      GLOAD_LDS16(bptr[j], &Bs[j * 2048 + wave * 512]);
#pragma unroll
    for (int j = 0; j < 4; ++j) { aptr[j] += BK; bptr[j] += BK; }
    __syncthreads();
#pragma unroll
    for (int s = 0; s < 2; ++s) {
      s8v af[4], bfr[4];
#pragma unroll
      for (int i2 = 0; i2 < 4; ++i2) {
        int ra = wm + i2 * 16 + l16;
        int rb = wn + i2 * 16 + l16;
        af[i2]  = *(const s8v*)(&As[ra * 64 + ((((s << 2) | quad) ^ (ra & 7)) * 8)]);
        bfr[i2] = *(const s8v*)(&Bs[rb * 64 + ((((s << 2) | quad) ^ (rb & 7)) * 8)]);
      }
#pragma unroll
      for (int mi = 0; mi < 4; ++mi)
#pragma unroll
        for (int ni = 0; ni < 4; ++ni)
          acc[mi][ni] = mfma_bf16(af[mi], bfr[ni], acc[mi][ni]);
    }
    __syncthreads();
  }

  if constexpr (OBF16) {
    // coalesced bf16 epilogue: restage each wave's 16x64 subtile through LDS
    unsigned short* Cs = smem + wave * 1088;   // 16 rows x 64 cols, stride 68
    float bvv[4];
#pragma unroll
    for (int ni = 0; ni < 4; ++ni) bvv[ni] = bias[n0 + wn + ni * 16 + l16];
    int row_l = lane >> 2, cg = lane & 3;
#pragma unroll
    for (int mi = 0; mi < 4; ++mi) {
#pragma unroll
      for (int ni = 0; ni < 4; ++ni) {
#pragma unroll
        for (int r = 0; r < 4; ++r) {
          float val = acc[mi][ni][r] + bvv[ni];
          if (relu) val = fmaxf(val, 0.f);
          Cs[(quad * 4 + r) * 68 + ni * 16 + l16] = f2bf(val);
        }
      }
      s8v v0 = *(const s8v*)(&Cs[row_l * 68 + cg * 16]);
      s8v v1 = *(const s8v*)(&Cs[row_l * 68 + cg * 16 + 8]);
      int grow = m0 + wm + mi * 16 + row_l;
      if (grow < M) {
        unsigned short* cp = (unsigned short*)Cp + (size_t)grow * N + n0 + wn + cg * 16;
        *(s8v*)cp = v0;
        *(s8v*)(cp + 8) = v1;
      }
    }
  } else {
#pragma unroll
    for (int ni = 0; ni < 4; ++ni) {
      int col = n0 + wn + ni * 16 + l16;
      float bv = bias[col];
#pragma unroll
      for (int mi = 0; mi < 4; ++mi) {
#pragma unroll
        for (int r = 0; r < 4; ++r) {
          int row = m0 + wm + mi * 16 + quad * 4 + r;
          if (row < M) {
            float val = acc[mi][ni][r] + bv;
            if (relu) val = fmaxf(val, 0.f);
            ((float*)Cp)[(size_t)row * N + col] = val;
          }
        }
      }
    }
  }
}

// ---------------- CSR build ----------------
__global__ void hist_kernel(const int* __restrict__ dst, int* __restrict__ cnt, int E) {
  int e = blockIdx.x * blockDim.x + threadIdx.x;
  if (e < E) atomicAdd(&cnt[dst[e]], 1);
}

__global__ void scan_kernel(const int* __restrict__ cnt, int* __restrict__ offs, int n) {
  __shared__ int sh[1024];
  __shared__ int carry_sh;
  int tid = threadIdx.x;
  if (tid == 0) carry_sh = 0;
  __syncthreads();
  for (int base = 0; base < n; base += 1024) {
    int v = (base + tid < n) ? cnt[base + tid] : 0;
    sh[tid] = v;
    __syncthreads();
    for (int s = 1; s < 1024; s <<= 1) {
      int t = (tid >= s) ? sh[tid - s] : 0;
      __syncthreads();
      sh[tid] += t;
      __syncthreads();
    }
    int carry = carry_sh;
    if (base + tid < n) offs[base + tid] = carry + sh[tid] - v;
    __syncthreads();
    if (tid == 1023) carry_sh = carry + sh[1023];
    __syncthreads();
  }
  if (tid == 0) offs[n] = carry_sh;
}

__global__ void scatter_kernel(const int* __restrict__ dst, const int* __restrict__ src,
                               const int* __restrict__ relations, const int* __restrict__ offs,
                               int* __restrict__ cursor, int* __restrict__ esrc,
                               int* __restrict__ erel, int E) {
  int e = blockIdx.x * blockDim.x + threadIdx.x;
  if (e < E) {
    int d = dst[e];
    int pos = offs[d] + atomicAdd(&cursor[d], 1);
    esrc[pos] = src[e];
    erel[pos] = relations[e];
  }
}

// ---------------- fused edge attention: one wave per dst node, online softmax ----------------
// lane = (head = lane>>3, chunk = lane&7); software-pipelined edge loop (prefetch i+1).
__global__ void edge_attn_kernel(const unsigned short* __restrict__ q,
                                 const unsigned short* __restrict__ k,
                                 const unsigned short* __restrict__ v,
                                 const unsigned short* __restrict__ relb,
                                 const int* __restrict__ offs,
                                 const int* __restrict__ esrc,
                                 const int* __restrict__ erel,
                                 unsigned short* __restrict__ o, int Nn, int STR) {
  int wid = (blockIdx.x * blockDim.x + threadIdx.x) >> 6;
  int lane = threadIdx.x & 63;
  if (wid >= Nn) return;
  int base = (lane >> 3) * HDK + (lane & 7) * 8;

  s8v qv = *(const s8v*)(q + (size_t)wid * STR + base);
  float qf[8];
#pragma unroll
  for (int j = 0; j < 8; ++j) qf[j] = bf2f((unsigned short)qv[j]);

  int beg = offs[wid], end = offs[wid + 1];
  float m = -1e30f, z = 0.f;
  float acc[8];
#pragma unroll
  for (int j = 0; j < 8; ++j) acc[j] = 0.f;

  s8v kv = {}, vv = {}, rv = {};
  if (beg < end) {
    int s0 = esrc[beg], r0 = erel[beg];
    kv = *(const s8v*)(k + (size_t)s0 * STR + base);
    vv = *(const s8v*)(v + (size_t)s0 * STR + base);
    rv = *(const s8v*)(relb + (size_t)r0 * HIDDEN + base);
  }
  for (int i = beg; i < end; ++i) {
    s8v kc = kv, vc = vv, rc = rv;
    if (i + 1 < end) {
      int sn = esrc[i + 1], rn = erel[i + 1];
      kv = *(const s8v*)(k + (size_t)sn * STR + base);
      vv = *(const s8v*)(v + (size_t)sn * STR + base);
      rv = *(const s8v*)(relb + (size_t)rn * HIDDEN + base);
    }
    float rf[8], p = 0.f;
#pragma unroll
    for (int j = 0; j < 8; ++j) {
      rf[j] = bf2f((unsigned short)rc[j]);
      p += (bf2f((unsigned short)kc[j]) + rf[j]) * qf[j];
    }
    p += __shfl_xor(p, 1, 64);
    p += __shfl_xor(p, 2, 64);
    p += __shfl_xor(p, 4, 64);
    p *= ATT_SCALE;
    float mn = fmaxf(m, p);
    float a = __expf(m - mn);
    float wgt = __expf(p - mn);
    z = z * a + wgt;
#pragma unroll
    for (int j = 0; j < 8; ++j)
      acc[j] = acc[j] * a + wgt * (bf2f((unsigned short)vc[j]) + rf[j]);
    m = mn;
  }
  float rz = 1.f / (z + 1e-9f);
  s8v ov;
#pragma unroll
  for (int j = 0; j < 8; ++j) ov[j] = (short)f2bf(acc[j] * rz);
  *(s8v*)(o + (size_t)wid * HIDDEN + base) = ov;
}

// ---------------- fused residual add + LayerNorm (one wave per row, bf16 in) ----------------
template <bool WF32>
__global__ void ln_kernel(const unsigned short* __restrict__ xp, const unsigned short* __restrict__ y,
                          const float* __restrict__ g, const float* __restrict__ b,
                          float* __restrict__ outf, unsigned short* __restrict__ outb, int Nn) {
  int wid = (blockIdx.x * blockDim.x + threadIdx.x) >> 6;
  int lane = threadIdx.x & 63;
  if (wid >= Nn) return;
  float vals[8];
  float sum = 0.f;
#pragma unroll
  for (int j = 0; j < 8; ++j) {
    int idx = j * 64 + lane;
    vals[j] = bf2f(xp[(size_t)wid * HIDDEN + idx]) + bf2f(y[(size_t)wid * HIDDEN + idx]);
    sum += vals[j];
  }
#pragma unroll
  for (int off = 32; off; off >>= 1) sum += __shfl_xor(sum, off, 64);
  float mean = sum * (1.f / 512.f);
  float sq = 0.f;
#pragma unroll
  for (int j = 0; j < 8; ++j) { float d = vals[j] - mean; sq += d * d; }
#pragma unroll
  for (int off = 32; off; off >>= 1) sq += __shfl_xor(sq, off, 64);
  float rstd = rsqrtf(sq * (1.f / 512.f) + 1e-5f);
#pragma unroll
  for (int j = 0; j < 8; ++j) {
    int idx = j * 64 + lane;
    float val = (vals[j] - mean) * rstd * g[idx] + b[idx];
    if constexpr (WF32) outf[(size_t)wid * HIDDEN + idx] = val;
    outb[(size_t)wid * HIDDEN + idx] = f2bf(val);
  }
}

// ---------------- host orchestration ----------------
extern "C" void kernel_launch(void* const* d_in, const int* in_sizes, int n_in,
                              void* d_out, int out_size, void* d_ws, size_t ws_size,
                              hipStream_t stream) {
  const float* x0        = (const float*)d_in[0];
  const int*   relations = (const int*)d_in[1];
  const int*   src       = (const int*)d_in[2];
  const int*   dst       = (const int*)d_in[3];
  const float* rel_embed = (const float*)d_in[4];
  const float* Wq = (const float*)d_in[5];  const float* bq = (const float*)d_in[6];
  const float* Wk = (const float*)d_in[7];  const float* bk = (const float*)d_in[8];
  const float* Wv = (const float*)d_in[9];  const float* bv = (const float*)d_in[10];
  const float* Wo = (const float*)d_in[11]; const float* bo = (const float*)d_in[12];
  const float* W1 = (const float*)d_in[13]; const float* b1 = (const float*)d_in[14];
  const float* W2 = (const float*)d_in[15]; const float* b2 = (const float*)d_in[16];
  const float* g1  = (const float*)d_in[17]; const float* bb1 = (const float*)d_in[18];
  const float* g2  = (const float*)d_in[19]; const float* bb2 = (const float*)d_in[20];
  float* xout = (float*)d_out;

  const size_t S1 = S1C;
  const size_t S2 = S2C;
  const size_t NH = (size_t)N_NODES * HIDDEN;   // 10,240,000

  // ---- workspace layout (~151 MiB) ----
  unsigned short* wqkv = (unsigned short*)d_ws; // 3*S1
  unsigned short* wo = wqkv + 3 * S1;
  unsigned short* w1 = wo + S1;                 // S2
  unsigned short* w2 = w1 + S2;                 // S2
  float* bqkv = (float*)(w2 + S2);              // 1536 fp32
  unsigned short* arena = (unsigned short*)(bqkv + 1536);  // 4*NH bf16
  unsigned short* qkvb = arena;                 // 3*NH, row stride 1536
  unsigned short* ob   = arena + 3 * NH;        // NH, row stride 512
  unsigned short* ff1  = arena;                 // 4*NH (qkv/ob dead by FF1 time)
  unsigned short* proj = arena;                 // NH bf16, aliases dead qkvb at Wo time
  unsigned short* hbb = arena + 4 * NH;         // NH bf16 (LN1 out)
  unsigned short* xb  = hbb + NH;               // NH bf16 (layer input / residual)
  unsigned short* projb = xb + NH;              // NH bf16 (FF2 out)
  unsigned short* relb  = projb + NH;           // 128*512 bf16
  int* cnt    = (int*)(relb + 65536);
  int* offs   = cnt + N_NODES;
  int* cursor = offs + N_NODES + 1;
  int* esrc   = cursor + N_NODES;
  int* erel   = esrc + N_EDGES;

  // ---- setup (once per call) ----
  hipMemsetAsync(cnt, 0, N_NODES * sizeof(int), stream);
  hipMemsetAsync(cursor, 0, N_NODES * sizeof(int), stream);
  hist_kernel<<<(N_EDGES + 255) / 256, 256, 0, stream>>>(dst, cnt, N_EDGES);
  scan_kernel<<<1, 1024, 0, stream>>>(cnt, offs, N_NODES);
  scatter_kernel<<<(N_EDGES + 255) / 256, 256, 0, stream>>>(dst, src, relations, offs, cursor, esrc, erel, N_EDGES);
  cast_kernel<<<(int)((NH + 255) / 256), 256, 0, stream>>>(x0, xb, (int)NH);
  cast_kernel<<<256, 256, 0, stream>>>(rel_embed, relb, 65536);

  const int MBc = (N_NODES + BM - 1) / BM;   // 157
  dim3 tb(32, 8);

  for (int l = 0; l < NLAYER; ++l) {
    // one-dispatch weight prep (6 transposes + bias concat)
    weight_prep_kernel<<<3078, tb, 0, stream>>>(Wq + l * S1, Wk + l * S1, Wv + l * S1, Wo + l * S1,
                                                W1 + l * S2, W2 + l * S2,
                                                bq + l * 512, bk + l * 512, bv + l * 512,
                                                wqkv, wo, w1, w2, bqkv);
    // merged QKV projection (bf16 A -> bf16 out, N=1536)
    gemm_bf16<true><<<dim3(12, MBc), 256, 0, stream>>>(xb, wqkv, bqkv, qkvb, N_NODES, 512, 1536, 0);
    // fused edge attention (pipelined edge loop)
    edge_attn_kernel<<<(N_NODES + 3) / 4, 256, 0, stream>>>(qkvb, qkvb + 512, qkvb + 1024,
                                                            relb, offs, esrc, erel, ob, N_NODES, 1536);
    // output projection -> bf16 proj, then LN1 -> hbb (bf16)
    gemm_bf16<true><<<dim3(4, MBc), 256, 0, stream>>>(ob, wo, bo + l * 512, proj, N_NODES, 512, 512, 0);
    ln_kernel<false><<<N_NODES / 4, 256, 0, stream>>>(xb, proj, g1 + l * 512, bb1 + l * 512, nullptr, hbb, N_NODES);
    // FFN: hbb -> ff1 (bf16, relu); ff1 -> projb (bf16)
    gemm_bf16<true><<<dim3(16, MBc), 256, 0, stream>>>(hbb, w1, b1 + l * 2048, ff1, N_NODES, 512, 2048, 1);
    gemm_bf16<true><<<dim3(4, MBc), 256, 0, stream>>>(ff1, w2, b2 + l * 512, projb, N_NODES, 2048, 512, 0);
    // LN2 -> xb (bf16 next-layer input/residual); final layer also writes fp32 xout
    if (l == NLAYER - 1)
      ln_kernel<true><<<N_NODES / 4, 256, 0, stream>>>(hbb, projb, g2 + l * 512, bb2 + l * 512, xout, xb, N_NODES);
    else
      ln_kernel<false><<<N_NODES / 4, 256, 0, stream>>>(hbb, projb, g2 + l * 512, bb2 + l * 512, nullptr, xb, N_NODES);
  }
}

// Round 9
// 1218.569 us; speedup vs baseline: 2.2563x; 1.0161x over previous
//
#include <hip/hip_runtime.h>
#include <cstdint>
#include <cstddef>

// ---------------- problem constants ----------------
#define N_NODES 20000
#define N_EDGES 160000
#define HIDDEN  512
#define NHEAD   8
#define HDK     64
#define NLAYER  4
#define FFDIM   2048
#define ATT_SCALE 0.125f   // 1/sqrt(64)
#define S1C 262144         // 512*512
#define S2C 1048576        // 512*2048
#define WLYR (4 * S1C + 2 * S2C)   // bf16 elems of prepped weights per layer

// ---------------- MFMA types ----------------
typedef float  f4  __attribute__((ext_vector_type(4)));
typedef short  s8v __attribute__((ext_vector_type(8)));
typedef __bf16 b8v __attribute__((ext_vector_type(8)));

template <typename V>
__device__ inline auto mfma_try(V a, V b, f4 c, int)
    -> decltype(__builtin_amdgcn_mfma_f32_16x16x32_bf16(a, b, c, 0, 0, 0)) {
  return __builtin_amdgcn_mfma_f32_16x16x32_bf16(a, b, c, 0, 0, 0);
}
template <typename V>
__device__ inline f4 mfma_try(V a, V b, f4 c, long) {
  return __builtin_amdgcn_mfma_f32_16x16x32_bf16(
      __builtin_bit_cast(b8v, a), __builtin_bit_cast(b8v, b), c, 0, 0, 0);
}
__device__ inline f4 mfma_bf16(s8v a, s8v b, f4 c) { return mfma_try(a, b, c, 0); }

__device__ __forceinline__ unsigned short f2bf(float f) {
  unsigned u = __builtin_bit_cast(unsigned, f);
  u += 0x7FFFu + ((u >> 16) & 1u);   // RNE
  return (unsigned short)(u >> 16);
}
__device__ __forceinline__ float bf2f(unsigned short u) {
  return __builtin_bit_cast(float, (unsigned)u << 16);
}

// async global->LDS, 16B per lane; LDS dest is wave-uniform base + lane*16
#define GLOAD_LDS16(gp, lp)                                                   \
  __builtin_amdgcn_global_load_lds(                                           \
      (const __attribute__((address_space(1))) void*)(gp),                    \
      (__attribute__((address_space(3))) void*)(lp), 16, 0, 0)

// ---------------- fp32 -> bf16 cast ----------------
__global__ void cast_kernel(const float* __restrict__ in, unsigned short* __restrict__ out, int n) {
  int i = blockIdx.x * blockDim.x + threadIdx.x;
  if (i < n) out[i] = f2bf(in[i]);
}

// ---------------- ALL-layer weight prep in ONE dispatch ----------------
// per layer: sub [0,1024) Wq/Wk/Wv/Wo 512x512; [1024,2048) W1; [2048,3072) W2;
// [3072,3078) bias concat. 3078 blocks/layer x 4 layers.
__global__ void weight_prep_kernel(const float* __restrict__ Wq, const float* __restrict__ Wk,
                                   const float* __restrict__ Wv, const float* __restrict__ Wo_,
                                   const float* __restrict__ W1, const float* __restrict__ W2,
                                   const float* __restrict__ bq, const float* __restrict__ bk,
                                   const float* __restrict__ bv,
                                   unsigned short* __restrict__ wAll, float* __restrict__ bqkvAll) {
  int l = blockIdx.x / 3078;
  int id = blockIdx.x % 3078;
  unsigned short* wqkv = wAll + (size_t)l * WLYR;
  unsigned short* wo = wqkv + 3 * S1C;
  unsigned short* w1 = wo + S1C;
  unsigned short* w2 = w1 + S2C;
  if (id >= 3072) {   // bias concat
    int i = (id - 3072) * 256 + threadIdx.y * 32 + threadIdx.x;
    float* bqkv = bqkvAll + l * 1536;
    if (i < 512) bqkv[i] = bq[l * 512 + i];
    else if (i < 1024) bqkv[i] = bk[l * 512 + i - 512];
    else if (i < 1536) bqkv[i] = bv[l * 512 + i - 1024];
    return;
  }
  const float* in; unsigned short* out; int K, N, bx, by;
  if (id < 1024) {
    int m = id >> 8, t = id & 255;
    in = ((m == 0) ? Wq : (m == 1) ? Wk : (m == 2) ? Wv : Wo_) + (size_t)l * S1C;
    out = (m == 3) ? wo : wqkv + m * S1C;
    K = 512; N = 512; bx = t & 15; by = t >> 4;
  } else if (id < 2048) {
    int t = id - 1024;
    in = W1 + (size_t)l * S2C; out = w1; K = 512; N = 2048; bx = t & 63; by = t >> 6;
  } else {
    int t = id - 2048;
    in = W2 + (size_t)l * S2C; out = w2; K = 2048; N = 512; bx = t & 15; by = t >> 4;
  }
  __shared__ float t32[32][33];
  int tx = threadIdx.x, ty = threadIdx.y;
  int n0 = bx * 32, k0 = by * 32;
#pragma unroll
  for (int i = 0; i < 32; i += 8)
    t32[ty + i][tx] = in[(size_t)(k0 + ty + i) * N + n0 + tx];
  __syncthreads();
#pragma unroll
  for (int i = 0; i < 32; i += 8)
    out[(size_t)(n0 + ty + i) * K + k0 + tx] = f2bf(t32[tx][ty + i]);
}

// ---------------- GEMM: C[M,N] = A[M,K] @ Bt[N,K]^T + bias, optional relu ----------------
// BK=64, XOR-swizzled LDS (chunk q of row r at pos q^(r&7)), XCD-aware block permutation.
// __launch_bounds__(256,3): force >=3 waves/EU (12 waves/CU = 3 blocks) so one block's
// epilogue overlaps neighbors' K-loops. 84+64 acc = 148 regs <= 512/3=170 -> no spill.
#define BM 128
#define BN 128
#define BK 64

template <bool OBF16>
__global__ __launch_bounds__(256, 3) void gemm_bf16(
    const unsigned short* __restrict__ A, const unsigned short* __restrict__ Bt,
    const float* __restrict__ bias, void* __restrict__ Cp,
    int M, int K, int N, int relu) {
  __shared__ __align__(16) unsigned short smem[16384];   // As [0,8192) Bs [8192,16384)
  unsigned short* As = smem;
  unsigned short* Bs = smem + 8192;
  int tid = threadIdx.x;
  int wave = tid >> 6, lane = tid & 63;
  int quad = lane >> 4, l16 = lane & 15;
  int wm = (wave >> 1) * 64, wn = (wave & 1) * 64;

  // XCD swizzle: contiguous work range per XCD
  int T = gridDim.x * gridDim.y;
  int i = blockIdx.y * gridDim.x + blockIdx.x;
  int C = T >> 3;
  int w = (i < (C << 3)) ? ((i & 7) * C + (i >> 3)) : i;
  int bx = w % gridDim.x, by = w / gridDim.x;
  int m0 = by * BM, n0 = bx * BN;

  f4 acc[4][4];
#pragma unroll
  for (int i2 = 0; i2 < 4; ++i2)
#pragma unroll
    for (int j = 0; j < 4; ++j) acc[i2][j] = (f4){0.f, 0.f, 0.f, 0.f};

  int rbase = wave * 8 + (lane >> 3);
  int q8 = (lane & 7) ^ ((lane >> 3) & 7);
  const unsigned short* aptr[4];
  const unsigned short* bptr[4];
#pragma unroll
  for (int j = 0; j < 4; ++j) {
    int r = j * 32 + rbase;
    int gm = m0 + r; if (gm >= M) gm = M - 1;   // clamp: dup rows never stored
    aptr[j] = A + (size_t)gm * K + q8 * 8;
    bptr[j] = Bt + (size_t)(n0 + r) * K + q8 * 8;
  }

  int nk = K >> 6;
  for (int ks = 0; ks < nk; ++ks) {
#pragma unroll
    for (int j = 0; j < 4; ++j)
      GLOAD_LDS16(aptr[j], &As[j * 2048 + wave * 512]);
#pragma unroll
    for (int j = 0; j < 4; ++j)
      GLOAD_LDS16(bptr[j], &Bs[j * 2048 + wave * 512]);
#pragma unroll
    for (int j = 0; j < 4; ++j) { aptr[j] += BK; bptr[j] += BK; }
    __syncthreads();
#pragma unroll
    for (int s = 0; s < 2; ++s) {
      s8v af[4], bfr[4];
#pragma unroll
      for (int i2 = 0; i2 < 4; ++i2) {
        int ra = wm + i2 * 16 + l16;
        int rb = wn + i2 * 16 + l16;
        af[i2]  = *(const s8v*)(&As[ra * 64 + ((((s << 2) | quad) ^ (ra & 7)) * 8)]);
        bfr[i2] = *(const s8v*)(&Bs[rb * 64 + ((((s << 2) | quad) ^ (rb & 7)) * 8)]);
      }
#pragma unroll
      for (int mi = 0; mi < 4; ++mi)
#pragma unroll
        for (int ni = 0; ni < 4; ++ni)
          acc[mi][ni] = mfma_bf16(af[mi], bfr[ni], acc[mi][ni]);
    }
    __syncthreads();
  }

  if constexpr (OBF16) {
    // coalesced bf16 epilogue: restage each wave's 16x64 subtile through LDS
    unsigned short* Cs = smem + wave * 1088;   // 16 rows x 64 cols, stride 68
    float bvv[4];
#pragma unroll
    for (int ni = 0; ni < 4; ++ni) bvv[ni] = bias[n0 + wn + ni * 16 + l16];
    int row_l = lane >> 2, cg = lane & 3;
#pragma unroll
    for (int mi = 0; mi < 4; ++mi) {
#pragma unroll
      for (int ni = 0; ni < 4; ++ni) {
#pragma unroll
        for (int r = 0; r < 4; ++r) {
          float val = acc[mi][ni][r] + bvv[ni];
          if (relu) val = fmaxf(val, 0.f);
          Cs[(quad * 4 + r) * 68 + ni * 16 + l16] = f2bf(val);
        }
      }
      s8v v0 = *(const s8v*)(&Cs[row_l * 68 + cg * 16]);
      s8v v1 = *(const s8v*)(&Cs[row_l * 68 + cg * 16 + 8]);
      int grow = m0 + wm + mi * 16 + row_l;
      if (grow < M) {
        unsigned short* cp = (unsigned short*)Cp + (size_t)grow * N + n0 + wn + cg * 16;
        *(s8v*)cp = v0;
        *(s8v*)(cp + 8) = v1;
      }
    }
  } else {
#pragma unroll
    for (int ni = 0; ni < 4; ++ni) {
      int col = n0 + wn + ni * 16 + l16;
      float bv = bias[col];
#pragma unroll
      for (int mi = 0; mi < 4; ++mi) {
#pragma unroll
        for (int r = 0; r < 4; ++r) {
          int row = m0 + wm + mi * 16 + quad * 4 + r;
          if (row < M) {
            float val = acc[mi][ni][r] + bv;
            if (relu) val = fmaxf(val, 0.f);
            ((float*)Cp)[(size_t)row * N + col] = val;
          }
        }
      }
    }
  }
}

// ---------------- CSR build ----------------
__global__ void hist_kernel(const int* __restrict__ dst, int* __restrict__ cnt, int E) {
  int e = blockIdx.x * blockDim.x + threadIdx.x;
  if (e < E) atomicAdd(&cnt[dst[e]], 1);
}

__global__ void scan_kernel(const int* __restrict__ cnt, int* __restrict__ offs, int n) {
  __shared__ int sh[1024];
  __shared__ int carry_sh;
  int tid = threadIdx.x;
  if (tid == 0) carry_sh = 0;
  __syncthreads();
  for (int base = 0; base < n; base += 1024) {
    int v = (base + tid < n) ? cnt[base + tid] : 0;
    sh[tid] = v;
    __syncthreads();
    for (int s = 1; s < 1024; s <<= 1) {
      int t = (tid >= s) ? sh[tid - s] : 0;
      __syncthreads();
      sh[tid] += t;
      __syncthreads();
    }
    int carry = carry_sh;
    if (base + tid < n) offs[base + tid] = carry + sh[tid] - v;
    __syncthreads();
    if (tid == 1023) carry_sh = carry + sh[1023];
    __syncthreads();
  }
  if (tid == 0) offs[n] = carry_sh;
}

__global__ void scatter_kernel(const int* __restrict__ dst, const int* __restrict__ src,
                               const int* __restrict__ relations, const int* __restrict__ offs,
                               int* __restrict__ cursor, int* __restrict__ esrc,
                               int* __restrict__ erel, int E) {
  int e = blockIdx.x * blockDim.x + threadIdx.x;
  if (e < E) {
    int d = dst[e];
    int pos = offs[d] + atomicAdd(&cursor[d], 1);
    esrc[pos] = src[e];
    erel[pos] = relations[e];
  }
}

// ---------------- fused edge attention: one wave per dst node, online softmax ----------------
// lane = (head = lane>>3, chunk = lane&7); software-pipelined edge loop (prefetch i+1).
__global__ void edge_attn_kernel(const unsigned short* __restrict__ q,
                                 const unsigned short* __restrict__ k,
                                 const unsigned short* __restrict__ v,
                                 const unsigned short* __restrict__ relb,
                                 const int* __restrict__ offs,
                                 const int* __restrict__ esrc,
                                 const int* __restrict__ erel,
                                 unsigned short* __restrict__ o, int Nn, int STR) {
  int wid = (blockIdx.x * blockDim.x + threadIdx.x) >> 6;
  int lane = threadIdx.x & 63;
  if (wid >= Nn) return;
  int base = (lane >> 3) * HDK + (lane & 7) * 8;

  s8v qv = *(const s8v*)(q + (size_t)wid * STR + base);
  float qf[8];
#pragma unroll
  for (int j = 0; j < 8; ++j) qf[j] = bf2f((unsigned short)qv[j]);

  int beg = offs[wid], end = offs[wid + 1];
  float m = -1e30f, z = 0.f;
  float acc[8];
#pragma unroll
  for (int j = 0; j < 8; ++j) acc[j] = 0.f;

  s8v kv = {}, vv = {}, rv = {};
  if (beg < end) {
    int s0 = esrc[beg], r0 = erel[beg];
    kv = *(const s8v*)(k + (size_t)s0 * STR + base);
    vv = *(const s8v*)(v + (size_t)s0 * STR + base);
    rv = *(const s8v*)(relb + (size_t)r0 * HIDDEN + base);
  }
  for (int i = beg; i < end; ++i) {
    s8v kc = kv, vc = vv, rc = rv;
    if (i + 1 < end) {
      int sn = esrc[i + 1], rn = erel[i + 1];
      kv = *(const s8v*)(k + (size_t)sn * STR + base);
      vv = *(const s8v*)(v + (size_t)sn * STR + base);
      rv = *(const s8v*)(relb + (size_t)rn * HIDDEN + base);
    }
    float rf[8], p = 0.f;
#pragma unroll
    for (int j = 0; j < 8; ++j) {
      rf[j] = bf2f((unsigned short)rc[j]);
      p += (bf2f((unsigned short)kc[j]) + rf[j]) * qf[j];
    }
    p += __shfl_xor(p, 1, 64);
    p += __shfl_xor(p, 2, 64);
    p += __shfl_xor(p, 4, 64);
    p *= ATT_SCALE;
    float mn = fmaxf(m, p);
    float a = __expf(m - mn);
    float wgt = __expf(p - mn);
    z = z * a + wgt;
#pragma unroll
    for (int j = 0; j < 8; ++j)
      acc[j] = acc[j] * a + wgt * (bf2f((unsigned short)vc[j]) + rf[j]);
    m = mn;
  }
  float rz = 1.f / (z + 1e-9f);
  s8v ov;
#pragma unroll
  for (int j = 0; j < 8; ++j) ov[j] = (short)f2bf(acc[j] * rz);
  *(s8v*)(o + (size_t)wid * HIDDEN + base) = ov;
}

// ---------------- fused residual add + LayerNorm (one wave per row, bf16 in) ----------------
template <bool WF32>
__global__ void ln_kernel(const unsigned short* __restrict__ xp, const unsigned short* __restrict__ y,
                          const float* __restrict__ g, const float* __restrict__ b,
                          float* __restrict__ outf, unsigned short* __restrict__ outb, int Nn) {
  int wid = (blockIdx.x * blockDim.x + threadIdx.x) >> 6;
  int lane = threadIdx.x & 63;
  if (wid >= Nn) return;
  float vals[8];
  float sum = 0.f;
#pragma unroll
  for (int j = 0; j < 8; ++j) {
    int idx = j * 64 + lane;
    vals[j] = bf2f(xp[(size_t)wid * HIDDEN + idx]) + bf2f(y[(size_t)wid * HIDDEN + idx]);
    sum += vals[j];
  }
#pragma unroll
  for (int off = 32; off; off >>= 1) sum += __shfl_xor(sum, off, 64);
  float mean = sum * (1.f / 512.f);
  float sq = 0.f;
#pragma unroll
  for (int j = 0; j < 8; ++j) { float d = vals[j] - mean; sq += d * d; }
#pragma unroll
  for (int off = 32; off; off >>= 1) sq += __shfl_xor(sq, off, 64);
  float rstd = rsqrtf(sq * (1.f / 512.f) + 1e-5f);
#pragma unroll
  for (int j = 0; j < 8; ++j) {
    int idx = j * 64 + lane;
    float val = (vals[j] - mean) * rstd * g[idx] + b[idx];
    if constexpr (WF32) outf[(size_t)wid * HIDDEN + idx] = val;
    outb[(size_t)wid * HIDDEN + idx] = f2bf(val);
  }
}

// ---------------- host orchestration ----------------
extern "C" void kernel_launch(void* const* d_in, const int* in_sizes, int n_in,
                              void* d_out, int out_size, void* d_ws, size_t ws_size,
                              hipStream_t stream) {
  const float* x0        = (const float*)d_in[0];
  const int*   relations = (const int*)d_in[1];
  const int*   src       = (const int*)d_in[2];
  const int*   dst       = (const int*)d_in[3];
  const float* rel_embed = (const float*)d_in[4];
  const float* Wq = (const float*)d_in[5];  const float* bq = (const float*)d_in[6];
  const float* Wk = (const float*)d_in[7];  const float* bk = (const float*)d_in[8];
  const float* Wv = (const float*)d_in[9];  const float* bv = (const float*)d_in[10];
  const float* Wo = (const float*)d_in[11]; const float* bo = (const float*)d_in[12];
  const float* W1 = (const float*)d_in[13]; const float* b1 = (const float*)d_in[14];
  const float* W2 = (const float*)d_in[15]; const float* b2 = (const float*)d_in[16];
  const float* g1  = (const float*)d_in[17]; const float* bb1 = (const float*)d_in[18];
  const float* g2  = (const float*)d_in[19]; const float* bb2 = (const float*)d_in[20];
  float* xout = (float*)d_out;

  const size_t S1 = S1C;
  const size_t S2 = S2C;
  const size_t NH = (size_t)N_NODES * HIDDEN;   // 10,240,000

  // ---- workspace layout (~163 MiB) ----
  unsigned short* wAll = (unsigned short*)d_ws;           // 4 * WLYR bf16 (all layers)
  float* bqkvAll = (float*)(wAll + (size_t)NLAYER * WLYR); // 4*1536 fp32
  unsigned short* arena = (unsigned short*)(bqkvAll + NLAYER * 1536);  // 4*NH bf16
  unsigned short* qkvb = arena;                 // 3*NH, row stride 1536
  unsigned short* ob   = arena + 3 * NH;        // NH, row stride 512
  unsigned short* ff1  = arena;                 // 4*NH (qkv/ob dead by FF1 time)
  unsigned short* proj = arena;                 // NH bf16, aliases dead qkvb at Wo time
  unsigned short* hbb = arena + 4 * NH;         // NH bf16 (LN1 out)
  unsigned short* xb  = hbb + NH;               // NH bf16 (layer input / residual)
  unsigned short* projb = xb + NH;              // NH bf16 (FF2 out)
  unsigned short* relb  = projb + NH;           // 128*512 bf16
  int* cnt    = (int*)(relb + 65536);
  int* offs   = cnt + N_NODES;
  int* cursor = offs + N_NODES + 1;
  int* esrc   = cursor + N_NODES;
  int* erel   = esrc + N_EDGES;

  // ---- setup (once per call) ----
  hipMemsetAsync(cnt, 0, N_NODES * sizeof(int), stream);
  hipMemsetAsync(cursor, 0, N_NODES * sizeof(int), stream);
  hist_kernel<<<(N_EDGES + 255) / 256, 256, 0, stream>>>(dst, cnt, N_EDGES);
  scan_kernel<<<1, 1024, 0, stream>>>(cnt, offs, N_NODES);
  scatter_kernel<<<(N_EDGES + 255) / 256, 256, 0, stream>>>(dst, src, relations, offs, cursor, esrc, erel, N_EDGES);
  cast_kernel<<<(int)((NH + 255) / 256), 256, 0, stream>>>(x0, xb, (int)NH);
  cast_kernel<<<256, 256, 0, stream>>>(rel_embed, relb, 65536);
  // all-layer weight prep, one dispatch
  dim3 tb(32, 8);
  weight_prep_kernel<<<NLAYER * 3078, tb, 0, stream>>>(Wq, Wk, Wv, Wo, W1, W2, bq, bk, bv,
                                                       wAll, bqkvAll);

  const int MBc = (N_NODES + BM - 1) / BM;   // 157

  for (int l = 0; l < NLAYER; ++l) {
    unsigned short* wqkv = wAll + (size_t)l * WLYR;
    unsigned short* wo = wqkv + 3 * S1;
    unsigned short* w1 = wo + S1;
    unsigned short* w2 = w1 + S2;
    float* bqkv = bqkvAll + l * 1536;
    // merged QKV projection (bf16 A -> bf16 out, N=1536)
    gemm_bf16<true><<<dim3(12, MBc), 256, 0, stream>>>(xb, wqkv, bqkv, qkvb, N_NODES, 512, 1536, 0);
    // fused edge attention (pipelined edge loop)
    edge_attn_kernel<<<(N_NODES + 3) / 4, 256, 0, stream>>>(qkvb, qkvb + 512, qkvb + 1024,
                                                            relb, offs, esrc, erel, ob, N_NODES, 1536);
    // output projection -> bf16 proj, then LN1 -> hbb (bf16)
    gemm_bf16<true><<<dim3(4, MBc), 256, 0, stream>>>(ob, wo, bo + l * 512, proj, N_NODES, 512, 512, 0);
    ln_kernel<false><<<N_NODES / 4, 256, 0, stream>>>(xb, proj, g1 + l * 512, bb1 + l * 512, nullptr, hbb, N_NODES);
    // FFN: hbb -> ff1 (bf16, relu); ff1 -> projb (bf16)
    gemm_bf16<true><<<dim3(16, MBc), 256, 0, stream>>>(hbb, w1, b1 + l * 2048, ff1, N_NODES, 512, 2048, 1);
    gemm_bf16<true><<<dim3(4, MBc), 256, 0, stream>>>(ff1, w2, b2 + l * 512, projb, N_NODES, 2048, 512, 0);
    // LN2 -> xb (bf16 next-layer input/residual); final layer also writes fp32 xout
    if (l == NLAYER - 1)
      ln_kernel<true><<<N_NODES / 4, 256, 0, stream>>>(hbb, projb, g2 + l * 512, bb2 + l * 512, xout, xb, N_NODES);
    else
      ln_kernel<false><<<N_NODES / 4, 256, 0, stream>>>(hbb, projb, g2 + l * 512, bb2 + l * 512, nullptr, xb, N_NODES);
  }
}

// Round 10
// 1214.704 us; speedup vs baseline: 2.2635x; 1.0032x over previous
//
#include <hip/hip_runtime.h>
#include <cstdint>
#include <cstddef>

// ---------------- problem constants ----------------
#define N_NODES 20000
#define N_EDGES 160000
#define HIDDEN  512
#define NHEAD   8
#define HDK     64
#define NLAYER  4
#define FFDIM   2048
#define ATT_SCALE 0.125f   // 1/sqrt(64)
#define S1C 262144         // 512*512
#define S2C 1048576        // 512*2048
#define WLYR (4 * S1C + 2 * S2C)   // bf16 elems of prepped weights per layer

// ---------------- MFMA types ----------------
typedef float  f4  __attribute__((ext_vector_type(4)));
typedef short  s8v __attribute__((ext_vector_type(8)));
typedef __bf16 b8v __attribute__((ext_vector_type(8)));

template <typename V>
__device__ inline auto mfma_try(V a, V b, f4 c, int)
    -> decltype(__builtin_amdgcn_mfma_f32_16x16x32_bf16(a, b, c, 0, 0, 0)) {
  return __builtin_amdgcn_mfma_f32_16x16x32_bf16(a, b, c, 0, 0, 0);
}
template <typename V>
__device__ inline f4 mfma_try(V a, V b, f4 c, long) {
  return __builtin_amdgcn_mfma_f32_16x16x32_bf16(
      __builtin_bit_cast(b8v, a), __builtin_bit_cast(b8v, b), c, 0, 0, 0);
}
__device__ inline f4 mfma_bf16(s8v a, s8v b, f4 c) { return mfma_try(a, b, c, 0); }

__device__ __forceinline__ unsigned short f2bf(float f) {
  unsigned u = __builtin_bit_cast(unsigned, f);
  u += 0x7FFFu + ((u >> 16) & 1u);   // RNE
  return (unsigned short)(u >> 16);
}
__device__ __forceinline__ float bf2f(unsigned short u) {
  return __builtin_bit_cast(float, (unsigned)u << 16);
}

// async global->LDS, 16B per lane; LDS dest is wave-uniform base + lane*16
#define GLOAD_LDS16(gp, lp)                                                   \
  __builtin_amdgcn_global_load_lds(                                           \
      (const __attribute__((address_space(1))) void*)(gp),                    \
      (__attribute__((address_space(3))) void*)(lp), 16, 0, 0)

// ---------------- fp32 -> bf16 cast ----------------
__global__ void cast_kernel(const float* __restrict__ in, unsigned short* __restrict__ out, int n) {
  int i = blockIdx.x * blockDim.x + threadIdx.x;
  if (i < n) out[i] = f2bf(in[i]);
}

// ---------------- ALL-layer weight prep in ONE dispatch ----------------
// Emits FRAGMENT-ORDERED bf16 weights: w[((nt*(K/8)+c)*16 + r)*8 + j] = W[c*8+j][nt*16+r]
// so a wave's B-fragment (16 rows x 4 k-chunks) is one contiguous 1024B block.
// per layer: sub [0,1024) Wq/Wk/Wv/Wo 512x512; [1024,2048) W1; [2048,3072) W2; [3072,3078) bias.
__global__ void weight_prep_kernel(const float* __restrict__ Wq, const float* __restrict__ Wk,
                                   const float* __restrict__ Wv, const float* __restrict__ Wo_,
                                   const float* __restrict__ W1, const float* __restrict__ W2,
                                   const float* __restrict__ bq, const float* __restrict__ bk,
                                   const float* __restrict__ bv,
                                   unsigned short* __restrict__ wAll, float* __restrict__ bqkvAll) {
  int l = blockIdx.x / 3078;
  int id = blockIdx.x % 3078;
  unsigned short* wqkv = wAll + (size_t)l * WLYR;
  unsigned short* wo = wqkv + 3 * S1C;
  unsigned short* w1 = wo + S1C;
  unsigned short* w2 = w1 + S2C;
  if (id >= 3072) {   // bias concat
    int i = (id - 3072) * 256 + threadIdx.y * 32 + threadIdx.x;
    float* bqkv = bqkvAll + l * 1536;
    if (i < 512) bqkv[i] = bq[l * 512 + i];
    else if (i < 1024) bqkv[i] = bk[l * 512 + i - 512];
    else if (i < 1536) bqkv[i] = bv[l * 512 + i - 1024];
    return;
  }
  const float* in; unsigned short* out; int K, N, bx, by;
  if (id < 1024) {
    int m = id >> 8, t = id & 255;
    in = ((m == 0) ? Wq : (m == 1) ? Wk : (m == 2) ? Wv : Wo_) + (size_t)l * S1C;
    out = (m == 3) ? wo : wqkv + m * S1C;
    K = 512; N = 512; bx = t & 15; by = t >> 4;
  } else if (id < 2048) {
    int t = id - 1024;
    in = W1 + (size_t)l * S2C; out = w1; K = 512; N = 2048; bx = t & 63; by = t >> 6;
  } else {
    int t = id - 2048;
    in = W2 + (size_t)l * S2C; out = w2; K = 2048; N = 512; bx = t & 15; by = t >> 4;
  }
  __shared__ float t32[32][33];
  int tx = threadIdx.x, ty = threadIdx.y;
  int n0 = bx * 32, k0 = by * 32;
  int Kc = K >> 3;
#pragma unroll
  for (int i = 0; i < 32; i += 8)
    t32[ty + i][tx] = in[(size_t)(k0 + ty + i) * N + n0 + tx];
  __syncthreads();
#pragma unroll
  for (int i = 0; i < 32; i += 8) {
    int n = n0 + ty + i, k = k0 + tx;
    size_t idx = ((size_t)(n >> 4) * Kc + (k >> 3)) * 128 + (n & 15) * 8 + (k & 7);
    out[idx] = f2bf(t32[tx][ty + i]);   // t32[tx][ty+i] = W[k][n]
  }
}

// ---------------- GEMM: C[M,N] = A[M,K] @ Bfrag[N,K]^T + bias, optional relu ----------------
// A staged via global_load_lds (BK=64, XOR swizzle). B read DIRECT from global in
// fragment order (L2-resident weights) -> halves LDS staging + halves ds_reads.
// XCD-aware block permutation; launch_bounds(256,3) for 3 blocks/CU.
#define BM 128
#define BN 128
#define BK 64

template <bool OBF16>
__global__ __launch_bounds__(256, 3) void gemm_bf16(
    const unsigned short* __restrict__ A, const unsigned short* __restrict__ Bt,
    const float* __restrict__ bias, void* __restrict__ Cp,
    int M, int K, int N, int relu) {
  __shared__ __align__(16) unsigned short As[8192];   // 128 x 64 bf16 (16 KB)
  int tid = threadIdx.x;
  int wave = tid >> 6, lane = tid & 63;
  int quad = lane >> 4, l16 = lane & 15;
  int wm = (wave >> 1) * 64, wn = (wave & 1) * 64;

  // XCD swizzle: contiguous work range per XCD
  int T = gridDim.x * gridDim.y;
  int i = blockIdx.y * gridDim.x + blockIdx.x;
  int C = T >> 3;
  int w = (i < (C << 3)) ? ((i & 7) * C + (i >> 3)) : i;
  int bx = w % gridDim.x, by = w / gridDim.x;
  int m0 = by * BM, n0 = bx * BN;

  f4 acc[4][4];
#pragma unroll
  for (int i2 = 0; i2 < 4; ++i2)
#pragma unroll
    for (int j = 0; j < 4; ++j) acc[i2][j] = (f4){0.f, 0.f, 0.f, 0.f};

  // A staging: round j covers rows [j*32, j*32+32); XOR-swizzled k-chunk
  int rbase = wave * 8 + (lane >> 3);
  int q8 = (lane & 7) ^ ((lane >> 3) & 7);
  const unsigned short* aptr[4];
#pragma unroll
  for (int j = 0; j < 4; ++j) {
    int r = j * 32 + rbase;
    int gm = m0 + r; if (gm >= M) gm = M - 1;   // clamp: dup rows never stored
    aptr[j] = A + (size_t)gm * K + q8 * 8;
  }

  // B fragment pointers: addr = (NT*(K/8) + c)*128 + l16*8, c = ks*8 + s*4 + quad
  int Kc = K >> 3;
  const unsigned short* bbase = Bt + quad * 128 + l16 * 8;
  size_t nioff[4];
#pragma unroll
  for (int i2 = 0; i2 < 4; ++i2)
    nioff[i2] = ((size_t)((n0 >> 4) + (wn >> 4) + i2) * Kc) * 128;

  int nk = K >> 6;
  for (int ks = 0; ks < nk; ++ks) {
#pragma unroll
    for (int j = 0; j < 4; ++j)
      GLOAD_LDS16(aptr[j], &As[j * 2048 + wave * 512]);
    // B loads issued alongside A staging; drained by the same pre-barrier vmcnt(0)
    s8v bfr[2][4];
#pragma unroll
    for (int s = 0; s < 2; ++s)
#pragma unroll
      for (int i2 = 0; i2 < 4; ++i2)
        bfr[s][i2] = *(const s8v*)(bbase + nioff[i2] + (size_t)ks * 1024 + s * 512);
#pragma unroll
    for (int j = 0; j < 4; ++j) aptr[j] += BK;
    __syncthreads();
#pragma unroll
    for (int s = 0; s < 2; ++s) {
      s8v af[4];
#pragma unroll
      for (int i2 = 0; i2 < 4; ++i2) {
        int ra = wm + i2 * 16 + l16;
        af[i2] = *(const s8v*)(&As[ra * 64 + ((((s << 2) | quad) ^ (ra & 7)) * 8)]);
      }
#pragma unroll
      for (int mi = 0; mi < 4; ++mi)
#pragma unroll
        for (int ni = 0; ni < 4; ++ni)
          acc[mi][ni] = mfma_bf16(af[mi], bfr[s][ni], acc[mi][ni]);
    }
    __syncthreads();
  }

  if constexpr (OBF16) {
    // coalesced bf16 epilogue: restage each wave's 16x64 subtile through LDS (reuse As)
    unsigned short* Cs = As + wave * 1088;   // 16 rows x 64 cols, stride 68
    float bvv[4];
#pragma unroll
    for (int ni = 0; ni < 4; ++ni) bvv[ni] = bias[n0 + wn + ni * 16 + l16];
    int row_l = lane >> 2, cg = lane & 3;
#pragma unroll
    for (int mi = 0; mi < 4; ++mi) {
#pragma unroll
      for (int ni = 0; ni < 4; ++ni) {
#pragma unroll
        for (int r = 0; r < 4; ++r) {
          float val = acc[mi][ni][r] + bvv[ni];
          if (relu) val = fmaxf(val, 0.f);
          Cs[(quad * 4 + r) * 68 + ni * 16 + l16] = f2bf(val);
        }
      }
      s8v v0 = *(const s8v*)(&Cs[row_l * 68 + cg * 16]);
      s8v v1 = *(const s8v*)(&Cs[row_l * 68 + cg * 16 + 8]);
      int grow = m0 + wm + mi * 16 + row_l;
      if (grow < M) {
        unsigned short* cp = (unsigned short*)Cp + (size_t)grow * N + n0 + wn + cg * 16;
        *(s8v*)cp = v0;
        *(s8v*)(cp + 8) = v1;
      }
    }
  } else {
#pragma unroll
    for (int ni = 0; ni < 4; ++ni) {
      int col = n0 + wn + ni * 16 + l16;
      float bv = bias[col];
#pragma unroll
      for (int mi = 0; mi < 4; ++mi) {
#pragma unroll
        for (int r = 0; r < 4; ++r) {
          int row = m0 + wm + mi * 16 + quad * 4 + r;
          if (row < M) {
            float val = acc[mi][ni][r] + bv;
            if (relu) val = fmaxf(val, 0.f);
            ((float*)Cp)[(size_t)row * N + col] = val;
          }
        }
      }
    }
  }
}

// ---------------- CSR build ----------------
__global__ void hist_kernel(const int* __restrict__ dst, int* __restrict__ cnt, int E) {
  int e = blockIdx.x * blockDim.x + threadIdx.x;
  if (e < E) atomicAdd(&cnt[dst[e]], 1);
}

__global__ void scan_kernel(const int* __restrict__ cnt, int* __restrict__ offs, int n) {
  __shared__ int sh[1024];
  __shared__ int carry_sh;
  int tid = threadIdx.x;
  if (tid == 0) carry_sh = 0;
  __syncthreads();
  for (int base = 0; base < n; base += 1024) {
    int v = (base + tid < n) ? cnt[base + tid] : 0;
    sh[tid] = v;
    __syncthreads();
    for (int s = 1; s < 1024; s <<= 1) {
      int t = (tid >= s) ? sh[tid - s] : 0;
      __syncthreads();
      sh[tid] += t;
      __syncthreads();
    }
    int carry = carry_sh;
    if (base + tid < n) offs[base + tid] = carry + sh[tid] - v;
    __syncthreads();
    if (tid == 1023) carry_sh = carry + sh[1023];
    __syncthreads();
  }
  if (tid == 0) offs[n] = carry_sh;
}

__global__ void scatter_kernel(const int* __restrict__ dst, const int* __restrict__ src,
                               const int* __restrict__ relations, const int* __restrict__ offs,
                               int* __restrict__ cursor, int* __restrict__ esrc,
                               int* __restrict__ erel, int E) {
  int e = blockIdx.x * blockDim.x + threadIdx.x;
  if (e < E) {
    int d = dst[e];
    int pos = offs[d] + atomicAdd(&cursor[d], 1);
    esrc[pos] = src[e];
    erel[pos] = relations[e];
  }
}

// ---------------- fused edge attention: one wave per dst node, online softmax ----------------
__global__ void edge_attn_kernel(const unsigned short* __restrict__ q,
                                 const unsigned short* __restrict__ k,
                                 const unsigned short* __restrict__ v,
                                 const unsigned short* __restrict__ relb,
                                 const int* __restrict__ offs,
                                 const int* __restrict__ esrc,
                                 const int* __restrict__ erel,
                                 unsigned short* __restrict__ o, int Nn, int STR) {
  int wid = (blockIdx.x * blockDim.x + threadIdx.x) >> 6;
  int lane = threadIdx.x & 63;
  if (wid >= Nn) return;
  int base = (lane >> 3) * HDK + (lane & 7) * 8;

  s8v qv = *(const s8v*)(q + (size_t)wid * STR + base);
  float qf[8];
#pragma unroll
  for (int j = 0; j < 8; ++j) qf[j] = bf2f((unsigned short)qv[j]);

  int beg = offs[wid], end = offs[wid + 1];
  float m = -1e30f, z = 0.f;
  float acc[8];
#pragma unroll
  for (int j = 0; j < 8; ++j) acc[j] = 0.f;

  s8v kv = {}, vv = {}, rv = {};
  if (beg < end) {
    int s0 = esrc[beg], r0 = erel[beg];
    kv = *(const s8v*)(k + (size_t)s0 * STR + base);
    vv = *(const s8v*)(v + (size_t)s0 * STR + base);
    rv = *(const s8v*)(relb + (size_t)r0 * HIDDEN + base);
  }
  for (int i = beg; i < end; ++i) {
    s8v kc = kv, vc = vv, rc = rv;
    if (i + 1 < end) {
      int sn = esrc[i + 1], rn = erel[i + 1];
      kv = *(const s8v*)(k + (size_t)sn * STR + base);
      vv = *(const s8v*)(v + (size_t)sn * STR + base);
      rv = *(const s8v*)(relb + (size_t)rn * HIDDEN + base);
    }
    float rf[8], p = 0.f;
#pragma unroll
    for (int j = 0; j < 8; ++j) {
      rf[j] = bf2f((unsigned short)rc[j]);
      p += (bf2f((unsigned short)kc[j]) + rf[j]) * qf[j];
    }
    p += __shfl_xor(p, 1, 64);
    p += __shfl_xor(p, 2, 64);
    p += __shfl_xor(p, 4, 64);
    p *= ATT_SCALE;
    float mn = fmaxf(m, p);
    float a = __expf(m - mn);
    float wgt = __expf(p - mn);
    z = z * a + wgt;
#pragma unroll
    for (int j = 0; j < 8; ++j)
      acc[j] = acc[j] * a + wgt * (bf2f((unsigned short)vc[j]) + rf[j]);
    m = mn;
  }
  float rz = 1.f / (z + 1e-9f);
  s8v ov;
#pragma unroll
  for (int j = 0; j < 8; ++j) ov[j] = (short)f2bf(acc[j] * rz);
  *(s8v*)(o + (size_t)wid * HIDDEN + base) = ov;
}

// ---------------- fused residual add + LayerNorm (one wave per row, bf16 in) ----------------
template <bool WF32>
__global__ void ln_kernel(const unsigned short* __restrict__ xp, const unsigned short* __restrict__ y,
                          const float* __restrict__ g, const float* __restrict__ b,
                          float* __restrict__ outf, unsigned short* __restrict__ outb, int Nn) {
  int wid = (blockIdx.x * blockDim.x + threadIdx.x) >> 6;
  int lane = threadIdx.x & 63;
  if (wid >= Nn) return;
  float vals[8];
  float sum = 0.f;
#pragma unroll
  for (int j = 0; j < 8; ++j) {
    int idx = j * 64 + lane;
    vals[j] = bf2f(xp[(size_t)wid * HIDDEN + idx]) + bf2f(y[(size_t)wid * HIDDEN + idx]);
    sum += vals[j];
  }
#pragma unroll
  for (int off = 32; off; off >>= 1) sum += __shfl_xor(sum, off, 64);
  float mean = sum * (1.f / 512.f);
  float sq = 0.f;
#pragma unroll
  for (int j = 0; j < 8; ++j) { float d = vals[j] - mean; sq += d * d; }
#pragma unroll
  for (int off = 32; off; off >>= 1) sq += __shfl_xor(sq, off, 64);
  float rstd = rsqrtf(sq * (1.f / 512.f) + 1e-5f);
#pragma unroll
  for (int j = 0; j < 8; ++j) {
    int idx = j * 64 + lane;
    float val = (vals[j] - mean) * rstd * g[idx] + b[idx];
    if constexpr (WF32) outf[(size_t)wid * HIDDEN + idx] = val;
    outb[(size_t)wid * HIDDEN + idx] = f2bf(val);
  }
}

// ---------------- host orchestration ----------------
extern "C" void kernel_launch(void* const* d_in, const int* in_sizes, int n_in,
                              void* d_out, int out_size, void* d_ws, size_t ws_size,
                              hipStream_t stream) {
  const float* x0        = (const float*)d_in[0];
  const int*   relations = (const int*)d_in[1];
  const int*   src       = (const int*)d_in[2];
  const int*   dst       = (const int*)d_in[3];
  const float* rel_embed = (const float*)d_in[4];
  const float* Wq = (const float*)d_in[5];  const float* bq = (const float*)d_in[6];
  const float* Wk = (const float*)d_in[7];  const float* bk = (const float*)d_in[8];
  const float* Wv = (const float*)d_in[9];  const float* bv = (const float*)d_in[10];
  const float* Wo = (const float*)d_in[11]; const float* bo = (const float*)d_in[12];
  const float* W1 = (const float*)d_in[13]; const float* b1 = (const float*)d_in[14];
  const float* W2 = (const float*)d_in[15]; const float* b2 = (const float*)d_in[16];
  const float* g1  = (const float*)d_in[17]; const float* bb1 = (const float*)d_in[18];
  const float* g2  = (const float*)d_in[19]; const float* bb2 = (const float*)d_in[20];
  float* xout = (float*)d_out;

  const size_t S1 = S1C;
  const size_t S2 = S2C;
  const size_t NH = (size_t)N_NODES * HIDDEN;   // 10,240,000

  // ---- workspace layout (~163 MiB) ----
  unsigned short* wAll = (unsigned short*)d_ws;           // 4 * WLYR bf16 (all layers, frag-ordered)
  float* bqkvAll = (float*)(wAll + (size_t)NLAYER * WLYR); // 4*1536 fp32
  unsigned short* arena = (unsigned short*)(bqkvAll + NLAYER * 1536);  // 4*NH bf16
  unsigned short* qkvb = arena;                 // 3*NH, row stride 1536
  unsigned short* ob   = arena + 3 * NH;        // NH, row stride 512
  unsigned short* ff1  = arena;                 // 4*NH (qkv/ob dead by FF1 time)
  unsigned short* proj = arena;                 // NH bf16, aliases dead qkvb at Wo time
  unsigned short* hbb = arena + 4 * NH;         // NH bf16 (LN1 out)
  unsigned short* xb  = hbb + NH;               // NH bf16 (layer input / residual)
  unsigned short* projb = xb + NH;              // NH bf16 (FF2 out)
  unsigned short* relb  = projb + NH;           // 128*512 bf16
  int* cnt    = (int*)(relb + 65536);
  int* offs   = cnt + N_NODES;
  int* cursor = offs + N_NODES + 1;
  int* esrc   = cursor + N_NODES;
  int* erel   = esrc + N_EDGES;

  // ---- setup (once per call) ----
  hipMemsetAsync(cnt, 0, N_NODES * sizeof(int), stream);
  hipMemsetAsync(cursor, 0, N_NODES * sizeof(int), stream);
  hist_kernel<<<(N_EDGES + 255) / 256, 256, 0, stream>>>(dst, cnt, N_EDGES);
  scan_kernel<<<1, 1024, 0, stream>>>(cnt, offs, N_NODES);
  scatter_kernel<<<(N_EDGES + 255) / 256, 256, 0, stream>>>(dst, src, relations, offs, cursor, esrc, erel, N_EDGES);
  cast_kernel<<<(int)((NH + 255) / 256), 256, 0, stream>>>(x0, xb, (int)NH);
  cast_kernel<<<256, 256, 0, stream>>>(rel_embed, relb, 65536);
  // all-layer weight prep, one dispatch
  dim3 tb(32, 8);
  weight_prep_kernel<<<NLAYER * 3078, tb, 0, stream>>>(Wq, Wk, Wv, Wo, W1, W2, bq, bk, bv,
                                                       wAll, bqkvAll);

  const int MBc = (N_NODES + BM - 1) / BM;   // 157

  for (int l = 0; l < NLAYER; ++l) {
    unsigned short* wqkv = wAll + (size_t)l * WLYR;
    unsigned short* wo = wqkv + 3 * S1;
    unsigned short* w1 = wo + S1;
    unsigned short* w2 = w1 + S2;
    float* bqkv = bqkvAll + l * 1536;
    // merged QKV projection (bf16 A -> bf16 out, N=1536)
    gemm_bf16<true><<<dim3(12, MBc), 256, 0, stream>>>(xb, wqkv, bqkv, qkvb, N_NODES, 512, 1536, 0);
    // fused edge attention (pipelined edge loop)
    edge_attn_kernel<<<(N_NODES + 3) / 4, 256, 0, stream>>>(qkvb, qkvb + 512, qkvb + 1024,
                                                            relb, offs, esrc, erel, ob, N_NODES, 1536);
    // output projection -> bf16 proj, then LN1 -> hbb (bf16)
    gemm_bf16<true><<<dim3(4, MBc), 256, 0, stream>>>(ob, wo, bo + l * 512, proj, N_NODES, 512, 512, 0);
    ln_kernel<false><<<N_NODES / 4, 256, 0, stream>>>(xb, proj, g1 + l * 512, bb1 + l * 512, nullptr, hbb, N_NODES);
    // FFN: hbb -> ff1 (bf16, relu); ff1 -> projb (bf16)
    gemm_bf16<true><<<dim3(16, MBc), 256, 0, stream>>>(hbb, w1, b1 + l * 2048, ff1, N_NODES, 512, 2048, 1);
    gemm_bf16<true><<<dim3(4, MBc), 256, 0, stream>>>(ff1, w2, b2 + l * 512, projb, N_NODES, 2048, 512, 0);
    // LN2 -> xb (bf16 next-layer input/residual); final layer also writes fp32 xout
    if (l == NLAYER - 1)
      ln_kernel<true><<<N_NODES / 4, 256, 0, stream>>>(hbb, projb, g2 + l * 512, bb2 + l * 512, xout, xb, N_NODES);
    else
      ln_kernel<false><<<N_NODES / 4, 256, 0, stream>>>(hbb, projb, g2 + l * 512, bb2 + l * 512, nullptr, xb, N_NODES);
  }
}